// Round 6
// baseline (160.393 us; speedup 1.0000x reference)
//
#include <hip/hip_runtime.h>
#include <hip/hip_bf16.h>

typedef __bf16 bf16x8 __attribute__((ext_vector_type(8)));
typedef float  f32x4  __attribute__((ext_vector_type(4)));

#define LOG2E 1.4426950408889634f
#define LN2   0.6931471805599453f

__device__ __forceinline__ float rcp_(float x){
#if __has_builtin(__builtin_amdgcn_rcpf)
  return __builtin_amdgcn_rcpf(x);
#else
  return 1.0f / x;
#endif
}
__device__ __forceinline__ float ex2_(float x){
#if __has_builtin(__builtin_amdgcn_exp2f)
  return __builtin_amdgcn_exp2f(x);
#else
  return exp2f(x);
#endif
}
__device__ __forceinline__ float lg2_(float x){
#if __has_builtin(__builtin_amdgcn_logf)
  return __builtin_amdgcn_logf(x);
#else
  return log2f(x);
#endif
}
// pre-scaled activations: inputs pre-multiplied by -LOG2E (sigmoid) / 2*LOG2E (tanh)
__device__ __forceinline__ float sigp_(float xp){ return rcp_(1.0f + ex2_(xp)); }
__device__ __forceinline__ float tanp_(float gp){ return 1.0f - 2.0f*rcp_(1.0f + ex2_(gp)); }

struct LstmArgs {
  const float* Wih[4]; const float* Whh[4];
  const float* bih[4]; const float* bhh[4];
  const float* h0[4];  const float* c0[4];
};

// ---------------------------------------------------------------------------
// pack_weights: fragment-lane-ordered, pre-scaled bf16x8 weight blobs +
// pre-scaled biases. wpack[((d*8+w)*4+g)*5+kk][lane] ; bpack[d*512 + grow]
// ---------------------------------------------------------------------------
__global__ void pack_weights(LstmArgs args, bf16x8* __restrict__ wpack,
                             float* __restrict__ bpack)
{
  const int idx = blockIdx.x*256 + threadIdx.x;      // 40960 total
  if (idx >= 4*8*4*5*64) return;
  const int lane = idx & 63;
  int r = idx >> 6;
  const int kk = r % 5; r /= 5;
  const int g  = r & 3; r >>= 2;
  const int w  = r & 7;
  const int d  = r >> 3;
  const int lc = lane & 15, lr4 = lane >> 4;
  const int grow = g*128 + w*16 + lc;
  const float sc = (g == 2) ? 2.0f*LOG2E : -LOG2E;

  bf16x8 v;
  if (kk < 4){
    const float* p = args.Whh[d] + grow*128 + kk*32 + lr4*8;
#pragma unroll
    for (int j = 0; j < 8; ++j) v[j] = (__bf16)(p[j] * sc);
  } else {
#pragma unroll
    for (int j = 0; j < 8; ++j){
      const int xi = lr4*8 + j;
      v[j] = (xi < 28) ? (__bf16)(args.Wih[d][grow*28 + xi] * sc) : (__bf16)0.0f;
    }
  }
  wpack[idx] = v;
  if (kk == 0 && lr4 == 0)
    bpack[d*512 + grow] = (args.bih[d][grow] + args.bhh[d][grow]) * sc;
}

// ---------------------------------------------------------------------------
// Kernel A: 4 dirs x 128 batch-blocks of 16 rows, 8 waves (512 thr).
// 512 blocks -> 2 blocks/CU co-resident (45.5 KiB LDS): cross-block overlap
// hides barrier + trans latency. Single barrier per step via double-buffered
// hcat (h written to buf^1; data-dep guarantees reads precede the barrier).
// Weights via coalesced wpack loads; x staged once (40-elem padded rows,
// 2-way-bank-free). featB written bf16 [batch][512].
// ---------------------------------------------------------------------------
__global__ __launch_bounds__(512, 4) void lstm4_kernel(const float* __restrict__ x,
                                                       LstmArgs args,
                                                       const bf16x8* __restrict__ wpack,
                                                       const float* __restrict__ bpack,
                                                       __bf16* __restrict__ featB)
{
  const int dir = blockIdx.x >> 7;          // 0=lr_f 1=lr_b 2=ud_f 3=ud_b
  const int b0  = (blockIdx.x & 127) * 16;
  const int tid = threadIdx.x;
  const int w   = tid >> 6;                 // wave 0..7
  const int l   = tid & 63;
  const int lc  = l & 15;
  const int lr4 = l >> 4;

  const float* __restrict__ h0 = args.h0[dir];
  const float* __restrict__ c0 = args.c0[dir];
  const int rev = dir & 1;
  const bool lrdir = (dir < 2);

  __shared__ __align__(16) __bf16 hcat[2][16 * 168];     // 10.5 KiB
  __shared__ __align__(16) __bf16 xstage[28 * 16 * 40];  // 35 KiB

  // ---- B fragments: coalesced 16B loads from wpack ------------------------
  bf16x8 bfr[4][5];
  float  bias[4];
  {
    const bf16x8* wp = wpack + (dir*8 + w)*4*5*64;
#pragma unroll
    for (int g = 0; g < 4; ++g){
#pragma unroll
      for (int kk = 0; kk < 5; ++kk)
        bfr[g][kk] = wp[(g*5 + kk)*64 + l];
      bias[g] = bpack[dir*512 + g*128 + w*16 + lc];
    }
  }

  // ---- stage x tile once, float4 global loads ------------------------------
  for (int idx = tid; idx < 16*196; idx += 512){   // 196 = 28*7 float4 per row
    const int row = idx / 196;
    const int rem = idx - row*196;
    if (lrdir){
      const int t = rem / 7, jg = rem - 7*t;
      const float4 v = *(const float4*)&x[(b0+row)*784 + t*28 + jg*4];
      __bf16* dst = &xstage[(t*16 + row)*40 + jg*4];
      dst[0]=(__bf16)v.x; dst[1]=(__bf16)v.y; dst[2]=(__bf16)v.z; dst[3]=(__bf16)v.w;
    } else {
      const int j = rem / 7, tg = rem - 7*j;
      const float4 v = *(const float4*)&x[(b0+row)*784 + j*28 + tg*4];
      xstage[((tg*4+0)*16 + row)*40 + j] = (__bf16)v.x;
      xstage[((tg*4+1)*16 + row)*40 + j] = (__bf16)v.y;
      xstage[((tg*4+2)*16 + row)*40 + j] = (__bf16)v.z;
      xstage[((tg*4+3)*16 + row)*40 + j] = (__bf16)v.w;
    }
  }
  if (tid < 28*16){                                // zero K-pad cols 28..31
    const int t = tid >> 4, row = tid & 15;
    __bf16* p = &xstage[(t*16 + row)*40 + 28];
    p[0] = p[1] = p[2] = p[3] = (__bf16)0.0f;
  }

  // ---- initial state -------------------------------------------------------
  float cst[4], hfin[4];
#pragma unroll
  for (int r = 0; r < 4; ++r){
    const int row = 4*lr4 + r;
    const int col = w*16 + lc;
    cst[r] = c0[(b0+row)*128 + col];
    hcat[0][row*168 + col] = (__bf16)h0[(b0+row)*128 + col];
    hfin[r] = 0.0f;
  }
  __syncthreads();

  // ---- 28 sequential steps, ONE barrier each -------------------------------
  int cur = 0;
  for (int s = 0; s < 28; ++s){
    const int t = rev ? (27 - s) : s;

    f32x4 acc[4];
#pragma unroll
    for (int g = 0; g < 4; ++g){
      f32x4 bv = {bias[g], bias[g], bias[g], bias[g]};
      acc[g] = bv;
    }
#pragma unroll
    for (int kk = 0; kk < 5; ++kk){
      const bf16x8 a = (kk < 4)
        ? *(const bf16x8*)&hcat[cur][lc*168 + kk*32 + lr4*8]
        : *(const bf16x8*)&xstage[(t*16 + lc)*40 + lr4*8];
#pragma unroll
      for (int g = 0; g < 4; ++g)
        acc[g] = __builtin_amdgcn_mfma_f32_16x16x32_bf16(a, bfr[g][kk], acc[g], 0, 0, 0);
    }

#pragma unroll
    for (int r = 0; r < 4; ++r){
      const float cc = sigp_(acc[1][r])*cst[r] + sigp_(acc[0][r])*tanp_(acc[2][r]);
      cst[r] = cc;
      const float hv = sigp_(acc[3][r])*tanp_(2.0f*LOG2E*cc);
      hfin[r] = hv;
      hcat[cur^1][(4*lr4 + r)*168 + w*16 + lc] = (__bf16)hv;
    }
    __syncthreads();
    cur ^= 1;
  }

  // ---- final h -> featB[batch][512] bf16 ----------------------------------
  {
    const int fcol = dir*128 + w*16 + lc;
#pragma unroll
    for (int r = 0; r < 4; ++r)
      featB[(b0 + 4*lr4 + r)*512 + fcol] = (__bf16)hfin[r];
  }
}

// ---------------------------------------------------------------------------
// Kernel B: fc LSTM, TWO batch elements per wave (shared weight regs,
// duplicated state) -> the second chain's instructions fill the first
// chain's trans/hazard stalls. Lanes = gate-rows 4u+g (40 active).
// xt via readlane from 64-step coalesced windows; quad_perm DPP gathers
// i/f/g/o; h back to SGPRs via readlanes. No LDS/DS, no barriers.
// ---------------------------------------------------------------------------
__global__ __launch_bounds__(256) void fc_lstm_wave(const ushort* __restrict__ featB,
                                                    const float* __restrict__ Wih,
                                                    const float* __restrict__ Whh,
                                                    const float* __restrict__ bih,
                                                    const float* __restrict__ bhh,
                                                    const float* __restrict__ h0,
                                                    const float* __restrict__ c0,
                                                    float* __restrict__ out)
{
  const int tid = threadIdx.x;
  const int l   = tid & 63;
  const int e0  = (blockIdx.x*4 + (tid >> 6)) * 2;   // elements e0, e0+1
  const int u   = l >> 2;                    // unit (valid < 10)
  const int g   = l & 3;                     // gate 0=i 1=f 2=g 3=o
  const int uc  = (u < 10) ? u : 9;
  const bool valid = (u < 10);
  const float sc = (g == 2) ? 2.0f*LOG2E : -LOG2E;
  const int row = g*10 + uc;

  float wh[10];
#pragma unroll
  for (int m = 0; m < 10; ++m) wh[m] = valid ? Whh[row*10 + m]*sc : 0.0f;
  const float wx   = valid ? Wih[row]*sc : 0.0f;
  const float bia  = valid ? (bih[row] + bhh[row])*sc : 0.0f;
  const float actA = (g == 2) ? 1.0f : 0.0f;
  const float actB = (g == 2) ? -2.0f : 1.0f;

  float c[2], hlast[2];
  float sh[2][10];
  int   vxc[2], vxn[2];
#pragma unroll
  for (int E = 0; E < 2; ++E){
    const int e = e0 + E;
    c[E]     = valid ? c0[e*10 + uc] : 0.0f;
    hlast[E] = valid ? h0[e*10 + uc] : 0.0f;
    const int hb = __float_as_int(hlast[E]);
#pragma unroll
    for (int m = 0; m < 10; ++m)
      sh[E][m] = __int_as_float(__builtin_amdgcn_readlane(hb, 4*m));
    vxc[E] = (int)featB[e*512 + l];
    vxn[E] = (int)featB[e*512 + 64 + l];
  }

  for (int win = 0; win < 8; ++win){
#pragma unroll 2
    for (int j = 0; j < 64; ++j){
#pragma unroll
      for (int E = 0; E < 2; ++E){
        const float xs = __int_as_float(__builtin_amdgcn_readlane(vxc[E], j) << 16);
        float a0 = __builtin_fmaf(wx, xs, bia);
        a0 = __builtin_fmaf(wh[0], sh[E][0], a0);
        float a1 = wh[1]*sh[E][1];
        a0 = __builtin_fmaf(wh[2], sh[E][2], a0); a1 = __builtin_fmaf(wh[3], sh[E][3], a1);
        a0 = __builtin_fmaf(wh[4], sh[E][4], a0); a1 = __builtin_fmaf(wh[5], sh[E][5], a1);
        a0 = __builtin_fmaf(wh[6], sh[E][6], a0); a1 = __builtin_fmaf(wh[7], sh[E][7], a1);
        a0 = __builtin_fmaf(wh[8], sh[E][8], a0); a1 = __builtin_fmaf(wh[9], sh[E][9], a1);
        const float acc = a0 + a1;
        const float rc  = rcp_(1.0f + ex2_(acc));
        const float val = __builtin_fmaf(actB, rc, actA);
        const int   vi  = __float_as_int(val);
        const float si  = __int_as_float(__builtin_amdgcn_mov_dpp(vi, 0x00, 0xF, 0xF, false));
        const float sf  = __int_as_float(__builtin_amdgcn_mov_dpp(vi, 0x55, 0xF, 0xF, false));
        const float tg  = __int_as_float(__builtin_amdgcn_mov_dpp(vi, 0xAA, 0xF, 0xF, false));
        const float so  = __int_as_float(__builtin_amdgcn_mov_dpp(vi, 0xFF, 0xF, 0xF, false));
        c[E] = __builtin_fmaf(sf, c[E], si*tg);
        const float tc = __builtin_fmaf(-2.0f, rcp_(1.0f + ex2_(2.0f*LOG2E*c[E])), 1.0f);
        const float h  = so*tc;
        hlast[E] = h;
        const int hbi = __float_as_int(h);
#pragma unroll
        for (int m = 0; m < 10; ++m)
          sh[E][m] = __int_as_float(__builtin_amdgcn_readlane(hbi, 4*m));
      }
    }
#pragma unroll
    for (int E = 0; E < 2; ++E){
      vxc[E] = vxn[E];
      if (win < 6) vxn[E] = (int)featB[(e0+E)*512 + (win+2)*64 + l];
    }
  }

  // ---- log-softmax over units 0..9 per element -----------------------------
#pragma unroll
  for (int E = 0; E < 2; ++E){
    float mx = sh[E][0];
#pragma unroll
    for (int m = 1; m < 10; ++m) mx = fmaxf(mx, sh[E][m]);
    float es = 0.0f;
#pragma unroll
    for (int m = 0; m < 10; ++m) es += ex2_(LOG2E*(sh[E][m] - mx));
    const float lse = LN2 * lg2_(es);
    if (valid && g == 0) out[(e0+E)*10 + u] = hlast[E] - mx - lse;
  }
}

extern "C" void kernel_launch(void* const* d_in, const int* in_sizes, int n_in,
                              void* d_out, int out_size, void* d_ws, size_t ws_size,
                              hipStream_t stream)
{
  const float* x = (const float*)d_in[0];
  LstmArgs a;
  const int base[4] = {1, 5, 9, 13};   // lr_f, lr_b, ud_f, ud_b
  for (int d = 0; d < 4; ++d){
    a.Wih[d] = (const float*)d_in[base[d] + 0];
    a.Whh[d] = (const float*)d_in[base[d] + 1];
    a.bih[d] = (const float*)d_in[base[d] + 2];
    a.bhh[d] = (const float*)d_in[base[d] + 3];
  }
  const float* h0lr = (const float*)d_in[21];
  const float* c0lr = (const float*)d_in[22];
  const float* h0ud = (const float*)d_in[23];
  const float* c0ud = (const float*)d_in[24];
  a.h0[0] = h0lr;               a.c0[0] = c0lr;
  a.h0[1] = h0lr + 2048*128;    a.c0[1] = c0lr + 2048*128;
  a.h0[2] = h0ud;               a.c0[2] = c0ud;
  a.h0[3] = h0ud + 2048*128;    a.c0[3] = c0ud + 2048*128;

  char* ws = (char*)d_ws;
  __bf16* featB = (__bf16*)ws;                          // 2048*512*2 = 2 MiB
  bf16x8* wpack = (bf16x8*)(ws + (2u<<20));             // 40960*16 = 640 KiB
  float*  bpack = (float*)(ws + (2u<<20) + 655360u);    // 2048*4 = 8 KiB

  pack_weights<<<160, 256, 0, stream>>>(a, wpack, bpack);
  lstm4_kernel<<<512, 512, 0, stream>>>(x, a, wpack, bpack, featB);
  fc_lstm_wave<<<256, 256, 0, stream>>>((const ushort*)featB,
      (const float*)d_in[17], (const float*)d_in[18],
      (const float*)d_in[19], (const float*)d_in[20],
      (const float*)d_in[25], (const float*)d_in[26],
      (float*)d_out);
}

// Round 8
// 139.705 us; speedup vs baseline: 1.1481x; 1.1481x over previous
//
#include <hip/hip_runtime.h>
#include <hip/hip_bf16.h>

typedef __bf16   bf16x8 __attribute__((ext_vector_type(8)));
typedef float    f32x4  __attribute__((ext_vector_type(4)));
typedef _Float16 h16x2  __attribute__((ext_vector_type(2)));

#define LOG2E 1.4426950408889634f
#define LN2   0.6931471805599453f

__device__ __forceinline__ float rcp_(float x){
#if __has_builtin(__builtin_amdgcn_rcpf)
  return __builtin_amdgcn_rcpf(x);
#else
  return 1.0f / x;
#endif
}
__device__ __forceinline__ float ex2_(float x){
#if __has_builtin(__builtin_amdgcn_exp2f)
  return __builtin_amdgcn_exp2f(x);
#else
  return exp2f(x);
#endif
}
__device__ __forceinline__ float lg2_(float x){
#if __has_builtin(__builtin_amdgcn_logf)
  return __builtin_amdgcn_logf(x);
#else
  return log2f(x);
#endif
}
// pre-scaled activations: inputs pre-multiplied by -LOG2E (sigmoid) / 2*LOG2E (tanh)
__device__ __forceinline__ float sigp_(float xp){ return rcp_(1.0f + ex2_(xp)); }
__device__ __forceinline__ float tanp_(float gp){ return 1.0f - 2.0f*rcp_(1.0f + ex2_(gp)); }

// pack two f32 -> f16x2 bit-pattern (int), and bit-cast helpers
__device__ __forceinline__ int pkrtz_(float a, float b){
  auto v = __builtin_amdgcn_cvt_pkrtz(a, b);
  int r; __builtin_memcpy(&r, &v, 4); return r;
}
__device__ __forceinline__ h16x2 as_h2_(int x){
  h16x2 r; __builtin_memcpy(&r, &x, 4); return r;
}

#if __has_builtin(__builtin_amdgcn_fdot2)
__device__ __forceinline__ float fdot2_(int w, int h, float a){
  return __builtin_amdgcn_fdot2(as_h2_(w), as_h2_(h), a, false);
}
#else
__device__ __forceinline__ float fdot2_(int w, int h, float a){
  h16x2 wv = as_h2_(w), hv = as_h2_(h);
  return a + (float)wv[0]*(float)hv[0] + (float)wv[1]*(float)hv[1];
}
#endif

struct LstmArgs {
  const float* Wih[4]; const float* Whh[4];
  const float* bih[4]; const float* bhh[4];
  const float* h0[4];  const float* c0[4];
};

// ---------------------------------------------------------------------------
// pack_weights: fragment-lane-ordered, pre-scaled bf16x8 weight blobs +
// pre-scaled biases. wpack[((d*8+w)*4+g)*5+kk][lane] ; bpack[d*512 + grow]
// ---------------------------------------------------------------------------
__global__ void pack_weights(LstmArgs args, bf16x8* __restrict__ wpack,
                             float* __restrict__ bpack)
{
  const int idx = blockIdx.x*256 + threadIdx.x;      // 40960 total
  if (idx >= 4*8*4*5*64) return;
  const int lane = idx & 63;
  int r = idx >> 6;
  const int kk = r % 5; r /= 5;
  const int g  = r & 3; r >>= 2;
  const int w  = r & 7;
  const int d  = r >> 3;
  const int lc = lane & 15, lr4 = lane >> 4;
  const int grow = g*128 + w*16 + lc;
  const float sc = (g == 2) ? 2.0f*LOG2E : -LOG2E;

  bf16x8 v;
  if (kk < 4){
    const float* p = args.Whh[d] + grow*128 + kk*32 + lr4*8;
#pragma unroll
    for (int j = 0; j < 8; ++j) v[j] = (__bf16)(p[j] * sc);
  } else {
#pragma unroll
    for (int j = 0; j < 8; ++j){
      const int xi = lr4*8 + j;
      v[j] = (xi < 28) ? (__bf16)(args.Wih[d][grow*28 + xi] * sc) : (__bf16)0.0f;
    }
  }
  wpack[idx] = v;
  if (kk == 0 && lr4 == 0)
    bpack[d*512 + grow] = (args.bih[d][grow] + args.bhh[d][grow]) * sc;
}

// ---------------------------------------------------------------------------
// Kernel A: 4 dirs x 64 batch-blocks of 32 rows, 8 waves (512 thr), 256
// blocks = 1/CU. Weights via coalesced wpack loads (regs). x staged once.
// Double-buffered hcat -> ONE barrier per step. Activations use fused
// reciprocals: sig(i)*tanh(g) = (Eg-1)*rcp((1+Ei)(1+Eg)) -> 8 trans/cell
// instead of 10 (trans issue is the dominant cost).
// ---------------------------------------------------------------------------
__global__ __launch_bounds__(512, 2) void lstm4_kernel(const float* __restrict__ x,
                                                       LstmArgs args,
                                                       const bf16x8* __restrict__ wpack,
                                                       const float* __restrict__ bpack,
                                                       __bf16* __restrict__ featB)
{
  const int dir = blockIdx.x >> 6;          // 0=lr_f 1=lr_b 2=ud_f 3=ud_b
  const int b0  = (blockIdx.x & 63) * 32;
  const int tid = threadIdx.x;
  const int w   = tid >> 6;                 // wave 0..7
  const int l   = tid & 63;
  const int lc  = l & 15;
  const int lr4 = l >> 4;

  const float* __restrict__ h0 = args.h0[dir];
  const float* __restrict__ c0 = args.c0[dir];
  const int rev = dir & 1;
  const bool lrdir = (dir < 2);

  __shared__ __align__(16) __bf16 hcat[2][32 * 168];     // 21 KiB
  __shared__ __align__(16) __bf16 xstage[28 * 32 * 40];  // 70 KiB

  // ---- B fragments: coalesced 16B loads from wpack ------------------------
  bf16x8 bfr[4][5];
  float  bias[4];
  {
    const bf16x8* wp = wpack + (dir*8 + w)*4*5*64;
#pragma unroll
    for (int g = 0; g < 4; ++g){
#pragma unroll
      for (int kk = 0; kk < 5; ++kk)
        bfr[g][kk] = wp[(g*5 + kk)*64 + l];
      bias[g] = bpack[dir*512 + g*128 + w*16 + lc];
    }
  }

  // ---- stage x tile once, float4 global loads ------------------------------
  for (int idx = tid; idx < 32*196; idx += 512){   // 196 = 28*7 float4 per row
    const int row = idx / 196;
    const int rem = idx - row*196;
    if (lrdir){
      const int t = rem / 7, jg = rem - 7*t;
      const float4 v = *(const float4*)&x[(b0+row)*784 + t*28 + jg*4];
      __bf16* dst = &xstage[(t*32 + row)*40 + jg*4];
      dst[0]=(__bf16)v.x; dst[1]=(__bf16)v.y; dst[2]=(__bf16)v.z; dst[3]=(__bf16)v.w;
    } else {
      const int j = rem / 7, tg = rem - 7*j;
      const float4 v = *(const float4*)&x[(b0+row)*784 + j*28 + tg*4];
      xstage[((tg*4+0)*32 + row)*40 + j] = (__bf16)v.x;
      xstage[((tg*4+1)*32 + row)*40 + j] = (__bf16)v.y;
      xstage[((tg*4+2)*32 + row)*40 + j] = (__bf16)v.z;
      xstage[((tg*4+3)*32 + row)*40 + j] = (__bf16)v.w;
    }
  }
  for (int idx = tid; idx < 28*32; idx += 512){    // zero K-pad cols 28..31
    const int t = idx >> 5, row = idx & 31;
    __bf16* p = &xstage[(t*32 + row)*40 + 28];
    p[0] = p[1] = p[2] = p[3] = (__bf16)0.0f;
  }

  // ---- initial state -------------------------------------------------------
  float cst[2][4];
#pragma unroll
  for (int m = 0; m < 2; ++m)
#pragma unroll
  for (int r = 0; r < 4; ++r){
    const int row = 16*m + 4*lr4 + r;
    const int col = w*16 + lc;
    cst[m][r] = c0[(b0+row)*128 + col];
    hcat[0][row*168 + col] = (__bf16)h0[(b0+row)*128 + col];
  }
  __syncthreads();

  // ---- 28 sequential steps, ONE barrier each -------------------------------
  int cur = 0;
  for (int s = 0; s < 28; ++s){
    const int t = rev ? (27 - s) : s;
    const int nxt = cur ^ 1;

    f32x4 acc[2][4];
#pragma unroll
    for (int m = 0; m < 2; ++m)
#pragma unroll
    for (int g = 0; g < 4; ++g){
      f32x4 bv = {bias[g], bias[g], bias[g], bias[g]};
      acc[m][g] = bv;
    }
#pragma unroll
    for (int m = 0; m < 2; ++m){
#pragma unroll
      for (int kk = 0; kk < 5; ++kk){
        const bf16x8 a = (kk < 4)
          ? *(const bf16x8*)&hcat[cur][(16*m + lc)*168 + kk*32 + lr4*8]
          : *(const bf16x8*)&xstage[(t*32 + 16*m + lc)*40 + lr4*8];
#pragma unroll
        for (int g = 0; g < 4; ++g)
          acc[m][g] = __builtin_amdgcn_mfma_f32_16x16x32_bf16(a, bfr[g][kk], acc[m][g], 0, 0, 0);
      }
    }

    // fused-rcp activations: 5 ex2 + 3 rcp per cell
#pragma unroll
    for (int m = 0; m < 2; ++m)
#pragma unroll
    for (int r = 0; r < 4; ++r){
      const float Ei = ex2_(acc[m][0][r]);   // e^{-i}
      const float Ef = ex2_(acc[m][1][r]);   // e^{-f}
      const float Eg = ex2_(acc[m][2][r]);   // e^{2g}
      const float Eo = ex2_(acc[m][3][r]);   // e^{-o}
      const float rf  = rcp_(1.0f + Ef);
      const float rig = rcp_((1.0f + Ei)*(1.0f + Eg));
      const float cc  = rf*cst[m][r] + (Eg - 1.0f)*rig;
      cst[m][r] = cc;
      const float Ec  = ex2_(2.0f*LOG2E*cc); // e^{2c}
      const float roc = rcp_((1.0f + Eo)*(1.0f + Ec));
      const float hv  = (Ec - 1.0f)*roc;     // sig(o)*tanh(c)
      hcat[nxt][(16*m + 4*lr4 + r)*168 + w*16 + lc] = (__bf16)hv;
    }
    __syncthreads();
    cur = nxt;
  }

  // ---- epilogue: final h (in hcat[cur]) -> featB[batch][512], coalesced ----
  {
    const int row = tid >> 4;      // 0..31
    const int cg  = tid & 15;      // 0..15
    const bf16x8 hv = *(const bf16x8*)&hcat[cur][row*168 + cg*8];
    *(bf16x8*)&featB[(b0+row)*512 + dir*128 + cg*8] = hv;
  }
}

// ---------------------------------------------------------------------------
// Kernel B: fc LSTM, one wave per batch element (2048 waves). Lanes =
// gate-rows 4u+g (40 active). Per step: xt via readlane from a 64-step
// coalesced window; h-dot via f16-packed fdot2 (5 readlanes of packed pairs
// built with ds_swizzle lane^4 + cvt_pkrtz); quad_perm DPP gathers i/f/g/o.
// No LDS tiles, no barriers.
// ---------------------------------------------------------------------------
__global__ __launch_bounds__(256) void fc_lstm_wave(const ushort* __restrict__ featB,
                                                    const float* __restrict__ Wih,
                                                    const float* __restrict__ Whh,
                                                    const float* __restrict__ bih,
                                                    const float* __restrict__ bhh,
                                                    const float* __restrict__ h0,
                                                    const float* __restrict__ c0,
                                                    float* __restrict__ out)
{
  const int tid = threadIdx.x;
  const int l   = tid & 63;
  const int e   = blockIdx.x*4 + (tid >> 6);
  const int u   = l >> 2;                    // unit (valid < 10)
  const int g   = l & 3;                     // gate 0=i 1=f 2=g 3=o
  const int uc  = (u < 10) ? u : 9;
  const bool valid = (u < 10);
  const float sc = (g == 2) ? 2.0f*LOG2E : -LOG2E;
  const int row = g*10 + uc;

  // weights packed f16 pairs: wh2[m] = (W[row][2m], W[row][2m+1]) * sc
  int wh2[5];
#pragma unroll
  for (int m = 0; m < 5; ++m){
    const float w0 = valid ? Whh[row*10 + 2*m]   * sc : 0.0f;
    const float w1 = valid ? Whh[row*10 + 2*m+1] * sc : 0.0f;
    wh2[m] = pkrtz_(w0, w1);
  }
  const float wx   = valid ? Wih[row]*sc : 0.0f;
  const float bia  = valid ? (bih[row] + bhh[row])*sc : 0.0f;
  const float actA = (g == 2) ? 1.0f : 0.0f;
  const float actB = (g == 2) ? -2.0f : 1.0f;

  float c     = valid ? c0[e*10 + uc] : 0.0f;
  float hlast = valid ? h0[e*10 + uc] : 0.0f;

  // packed h broadcast: lane 4u gets (h[u], h[u^1]); read pairs from lanes
  // 0,8,16,24,32 (units 0,2,4,6,8 -> pairs (0,1),(2,3),(4,5),(6,7),(8,9)).
  int hp0, hp1, hp2, hp3, hp4;
  {
    const float hnb = __int_as_float(
        __builtin_amdgcn_ds_swizzle(__float_as_int(hlast), 0x101F)); // lane^4
    const int hpi = pkrtz_(hlast, hnb);
    hp0 = __builtin_amdgcn_readlane(hpi,  0);
    hp1 = __builtin_amdgcn_readlane(hpi,  8);
    hp2 = __builtin_amdgcn_readlane(hpi, 16);
    hp3 = __builtin_amdgcn_readlane(hpi, 24);
    hp4 = __builtin_amdgcn_readlane(hpi, 32);
  }

  const ushort* fB = featB + e*512;
  int vxc = (int)fB[l];            // steps 0..63 (bf16 bits, zero-extended)
  int vxn = (int)fB[64 + l];       // steps 64..127

  for (int win = 0; win < 8; ++win){
#pragma unroll 4
    for (int j = 0; j < 64; ++j){
      const float xs = __int_as_float(__builtin_amdgcn_readlane(vxc, j) << 16);
      float a0 = __builtin_fmaf(wx, xs, bia);
      a0 = fdot2_(wh2[0], hp0, a0);
      float a1 = fdot2_(wh2[1], hp1, 0.0f);
      a0 = fdot2_(wh2[2], hp2, a0);
      a1 = fdot2_(wh2[3], hp3, a1);
      a0 = fdot2_(wh2[4], hp4, a0);
      const float acc = a0 + a1;
      const float rc  = rcp_(1.0f + ex2_(acc));
      const float val = __builtin_fmaf(actB, rc, actA);
      const int   vi  = __float_as_int(val);
      const float si  = __int_as_float(__builtin_amdgcn_mov_dpp(vi, 0x00, 0xF, 0xF, false));
      const float sf  = __int_as_float(__builtin_amdgcn_mov_dpp(vi, 0x55, 0xF, 0xF, false));
      const float tg  = __int_as_float(__builtin_amdgcn_mov_dpp(vi, 0xAA, 0xF, 0xF, false));
      const float so  = __int_as_float(__builtin_amdgcn_mov_dpp(vi, 0xFF, 0xF, 0xF, false));
      c = __builtin_fmaf(sf, c, si*tg);
      const float tc = __builtin_fmaf(-2.0f, rcp_(1.0f + ex2_(2.0f*LOG2E*c)), 1.0f);
      const float h  = so*tc;
      hlast = h;
      const float hnb = __int_as_float(
          __builtin_amdgcn_ds_swizzle(__float_as_int(h), 0x101F));
      const int hpi = pkrtz_(h, hnb);
      hp0 = __builtin_amdgcn_readlane(hpi,  0);
      hp1 = __builtin_amdgcn_readlane(hpi,  8);
      hp2 = __builtin_amdgcn_readlane(hpi, 16);
      hp3 = __builtin_amdgcn_readlane(hpi, 24);
      hp4 = __builtin_amdgcn_readlane(hpi, 32);
    }
    vxc = vxn;
    if (win < 6) vxn = (int)fB[(win+2)*64 + l];
  }

  // ---- log-softmax over units 0..9 (exact f32 h via plain readlanes) -------
  const int hb = __float_as_int(hlast);
  float sh[10];
#pragma unroll
  for (int m = 0; m < 10; ++m)
    sh[m] = __int_as_float(__builtin_amdgcn_readlane(hb, 4*m));
  float mx = sh[0];
#pragma unroll
  for (int m = 1; m < 10; ++m) mx = fmaxf(mx, sh[m]);
  float es = 0.0f;
#pragma unroll
  for (int m = 0; m < 10; ++m) es += ex2_(LOG2E*(sh[m] - mx));
  const float lse = LN2 * lg2_(es);
  if (valid && g == 0) out[e*10 + u] = hlast - mx - lse;
}

extern "C" void kernel_launch(void* const* d_in, const int* in_sizes, int n_in,
                              void* d_out, int out_size, void* d_ws, size_t ws_size,
                              hipStream_t stream)
{
  const float* x = (const float*)d_in[0];
  LstmArgs a;
  const int base[4] = {1, 5, 9, 13};   // lr_f, lr_b, ud_f, ud_b
  for (int d = 0; d < 4; ++d){
    a.Wih[d] = (const float*)d_in[base[d] + 0];
    a.Whh[d] = (const float*)d_in[base[d] + 1];
    a.bih[d] = (const float*)d_in[base[d] + 2];
    a.bhh[d] = (const float*)d_in[base[d] + 3];
  }
  const float* h0lr = (const float*)d_in[21];
  const float* c0lr = (const float*)d_in[22];
  const float* h0ud = (const float*)d_in[23];
  const float* c0ud = (const float*)d_in[24];
  a.h0[0] = h0lr;               a.c0[0] = c0lr;
  a.h0[1] = h0lr + 2048*128;    a.c0[1] = c0lr + 2048*128;
  a.h0[2] = h0ud;               a.c0[2] = c0ud;
  a.h0[3] = h0ud + 2048*128;    a.c0[3] = c0ud + 2048*128;

  char* ws = (char*)d_ws;
  __bf16* featB = (__bf16*)ws;                          // 2048*512*2 = 2 MiB
  bf16x8* wpack = (bf16x8*)(ws + (2u<<20));             // 40960*16 = 640 KiB
  float*  bpack = (float*)(ws + (2u<<20) + 655360u);    // 2048*4 = 8 KiB

  pack_weights<<<160, 256, 0, stream>>>(a, wpack, bpack);
  lstm4_kernel<<<256, 512, 0, stream>>>(x, a, wpack, bpack, featB);
  fc_lstm_wave<<<512, 256, 0, stream>>>((const ushort*)featB,
      (const float*)d_in[17], (const float*)d_in[18],
      (const float*)d_in[19], (const float*)d_in[20],
      (const float*)d_in[25], (const float*)d_in[26],
      (float*)d_out);
}

// Round 9
// 137.724 us; speedup vs baseline: 1.1646x; 1.0144x over previous
//
#include <hip/hip_runtime.h>
#include <hip/hip_bf16.h>

typedef __bf16   bf16x8 __attribute__((ext_vector_type(8)));
typedef float    f32x4  __attribute__((ext_vector_type(4)));

#define LOG2E 1.4426950408889634f
#define LN2   0.6931471805599453f

__device__ __forceinline__ float rcp_(float x){
#if __has_builtin(__builtin_amdgcn_rcpf)
  return __builtin_amdgcn_rcpf(x);
#else
  return 1.0f / x;
#endif
}
__device__ __forceinline__ float ex2_(float x){
#if __has_builtin(__builtin_amdgcn_exp2f)
  return __builtin_amdgcn_exp2f(x);
#else
  return exp2f(x);
#endif
}
__device__ __forceinline__ float lg2_(float x){
#if __has_builtin(__builtin_amdgcn_logf)
  return __builtin_amdgcn_logf(x);
#else
  return log2f(x);
#endif
}

struct LstmArgs {
  const float* Wih[4]; const float* Whh[4];
  const float* bih[4]; const float* bhh[4];
  const float* h0[4];  const float* c0[4];
};

// ---------------------------------------------------------------------------
// pack_weights: fragment-lane-ordered, pre-scaled bf16x8 weight blobs +
// pre-scaled biases. wpack[((d*8+w)*4+g)*5+kk][lane] ; bpack[d*512 + grow]
// ---------------------------------------------------------------------------
__global__ void pack_weights(LstmArgs args, bf16x8* __restrict__ wpack,
                             float* __restrict__ bpack)
{
  const int idx = blockIdx.x*256 + threadIdx.x;      // 40960 total
  if (idx >= 4*8*4*5*64) return;
  const int lane = idx & 63;
  int r = idx >> 6;
  const int kk = r % 5; r /= 5;
  const int g  = r & 3; r >>= 2;
  const int w  = r & 7;
  const int d  = r >> 3;
  const int lc = lane & 15, lr4 = lane >> 4;
  const int grow = g*128 + w*16 + lc;
  const float sc = (g == 2) ? 2.0f*LOG2E : -LOG2E;

  bf16x8 v;
  if (kk < 4){
    const float* p = args.Whh[d] + grow*128 + kk*32 + lr4*8;
#pragma unroll
    for (int j = 0; j < 8; ++j) v[j] = (__bf16)(p[j] * sc);
  } else {
#pragma unroll
    for (int j = 0; j < 8; ++j){
      const int xi = lr4*8 + j;
      v[j] = (xi < 28) ? (__bf16)(args.Wih[d][grow*28 + xi] * sc) : (__bf16)0.0f;
    }
  }
  wpack[idx] = v;
  if (kk == 0 && lr4 == 0)
    bpack[d*512 + grow] = (args.bih[d][grow] + args.bhh[d][grow]) * sc;
}

// ---------------------------------------------------------------------------
// Kernel A: 4 dirs x 64 batch-blocks of 32 rows, 8 waves (512 thr), 256
// blocks = 1/CU. Weights via coalesced wpack loads (regs). x staged once.
// Double-buffered hcat -> ONE barrier per step. Fused-rcp activations:
// 5 ex2 + 3 rcp per cell.
// ---------------------------------------------------------------------------
__global__ __launch_bounds__(512, 2) void lstm4_kernel(const float* __restrict__ x,
                                                       LstmArgs args,
                                                       const bf16x8* __restrict__ wpack,
                                                       const float* __restrict__ bpack,
                                                       __bf16* __restrict__ featB)
{
  const int dir = blockIdx.x >> 6;          // 0=lr_f 1=lr_b 2=ud_f 3=ud_b
  const int b0  = (blockIdx.x & 63) * 32;
  const int tid = threadIdx.x;
  const int w   = tid >> 6;                 // wave 0..7
  const int l   = tid & 63;
  const int lc  = l & 15;
  const int lr4 = l >> 4;

  const float* __restrict__ h0 = args.h0[dir];
  const float* __restrict__ c0 = args.c0[dir];
  const int rev = dir & 1;
  const bool lrdir = (dir < 2);

  __shared__ __align__(16) __bf16 hcat[2][32 * 168];     // 21 KiB
  __shared__ __align__(16) __bf16 xstage[28 * 32 * 40];  // 70 KiB

  // ---- B fragments: coalesced 16B loads from wpack ------------------------
  bf16x8 bfr[4][5];
  float  bias[4];
  {
    const bf16x8* wp = wpack + (dir*8 + w)*4*5*64;
#pragma unroll
    for (int g = 0; g < 4; ++g){
#pragma unroll
      for (int kk = 0; kk < 5; ++kk)
        bfr[g][kk] = wp[(g*5 + kk)*64 + l];
      bias[g] = bpack[dir*512 + g*128 + w*16 + lc];
    }
  }

  // ---- stage x tile once, float4 global loads ------------------------------
  for (int idx = tid; idx < 32*196; idx += 512){   // 196 = 28*7 float4 per row
    const int row = idx / 196;
    const int rem = idx - row*196;
    if (lrdir){
      const int t = rem / 7, jg = rem - 7*t;
      const float4 v = *(const float4*)&x[(b0+row)*784 + t*28 + jg*4];
      __bf16* dst = &xstage[(t*32 + row)*40 + jg*4];
      dst[0]=(__bf16)v.x; dst[1]=(__bf16)v.y; dst[2]=(__bf16)v.z; dst[3]=(__bf16)v.w;
    } else {
      const int j = rem / 7, tg = rem - 7*j;
      const float4 v = *(const float4*)&x[(b0+row)*784 + j*28 + tg*4];
      xstage[((tg*4+0)*32 + row)*40 + j] = (__bf16)v.x;
      xstage[((tg*4+1)*32 + row)*40 + j] = (__bf16)v.y;
      xstage[((tg*4+2)*32 + row)*40 + j] = (__bf16)v.z;
      xstage[((tg*4+3)*32 + row)*40 + j] = (__bf16)v.w;
    }
  }
  for (int idx = tid; idx < 28*32; idx += 512){    // zero K-pad cols 28..31
    const int t = idx >> 5, row = idx & 31;
    __bf16* p = &xstage[(t*32 + row)*40 + 28];
    p[0] = p[1] = p[2] = p[3] = (__bf16)0.0f;
  }

  // ---- initial state -------------------------------------------------------
  float cst[2][4];
#pragma unroll
  for (int m = 0; m < 2; ++m)
#pragma unroll
  for (int r = 0; r < 4; ++r){
    const int row = 16*m + 4*lr4 + r;
    const int col = w*16 + lc;
    cst[m][r] = c0[(b0+row)*128 + col];
    hcat[0][row*168 + col] = (__bf16)h0[(b0+row)*128 + col];
  }
  __syncthreads();

  // ---- 28 sequential steps, ONE barrier each -------------------------------
  int cur = 0;
  for (int s = 0; s < 28; ++s){
    const int t = rev ? (27 - s) : s;
    const int nxt = cur ^ 1;

    f32x4 acc[2][4];
#pragma unroll
    for (int m = 0; m < 2; ++m)
#pragma unroll
    for (int g = 0; g < 4; ++g){
      f32x4 bv = {bias[g], bias[g], bias[g], bias[g]};
      acc[m][g] = bv;
    }
#pragma unroll
    for (int m = 0; m < 2; ++m){
#pragma unroll
      for (int kk = 0; kk < 5; ++kk){
        const bf16x8 a = (kk < 4)
          ? *(const bf16x8*)&hcat[cur][(16*m + lc)*168 + kk*32 + lr4*8]
          : *(const bf16x8*)&xstage[(t*32 + 16*m + lc)*40 + lr4*8];
#pragma unroll
        for (int g = 0; g < 4; ++g)
          acc[m][g] = __builtin_amdgcn_mfma_f32_16x16x32_bf16(a, bfr[g][kk], acc[m][g], 0, 0, 0);
      }
    }

    // fused-rcp activations: 5 ex2 + 3 rcp per cell
#pragma unroll
    for (int m = 0; m < 2; ++m)
#pragma unroll
    for (int r = 0; r < 4; ++r){
      const float Ei = ex2_(acc[m][0][r]);   // e^{-i}
      const float Ef = ex2_(acc[m][1][r]);   // e^{-f}
      const float Eg = ex2_(acc[m][2][r]);   // e^{2g}
      const float Eo = ex2_(acc[m][3][r]);   // e^{-o}
      const float rf  = rcp_(1.0f + Ef);
      const float rig = rcp_((1.0f + Ei)*(1.0f + Eg));
      const float cc  = rf*cst[m][r] + (Eg - 1.0f)*rig;
      cst[m][r] = cc;
      const float Ec  = ex2_(2.0f*LOG2E*cc); // e^{2c}
      const float roc = rcp_((1.0f + Eo)*(1.0f + Ec));
      const float hv  = (Ec - 1.0f)*roc;     // sig(o)*tanh(c)
      hcat[nxt][(16*m + 4*lr4 + r)*168 + w*16 + lc] = (__bf16)hv;
    }
    __syncthreads();
    cur = nxt;
  }

  // ---- epilogue: final h (in hcat[cur]) -> featB[batch][512], coalesced ----
  {
    const int row = tid >> 4;      // 0..31
    const int cg  = tid & 15;      // 0..15
    const bf16x8 hv = *(const bf16x8*)&hcat[cur][row*168 + cg*8];
    *(bf16x8*)&featB[(b0+row)*512 + dir*128 + cg*8] = hv;
  }
}

// ---------------------------------------------------------------------------
// Kernel B: fc LSTM, one wave per batch element (2048 waves, 2/SIMD).
// Lanes = gate-rows 4u+g (40 active). Per step: xt via readlane from a
// 64-step coalesced window; h broadcast via 10 plain readlanes (VALU-domain,
// no DS latency); dot as a 4-accumulator TREE (depth 3 FMA + 2 add);
// quad_perm DPP gathers i/f/g/o. No LDS, no barriers.
// ---------------------------------------------------------------------------
__global__ __launch_bounds__(256) void fc_lstm_wave(const ushort* __restrict__ featB,
                                                    const float* __restrict__ Wih,
                                                    const float* __restrict__ Whh,
                                                    const float* __restrict__ bih,
                                                    const float* __restrict__ bhh,
                                                    const float* __restrict__ h0,
                                                    const float* __restrict__ c0,
                                                    float* __restrict__ out)
{
  const int tid = threadIdx.x;
  const int l   = tid & 63;
  const int e   = blockIdx.x*4 + (tid >> 6);
  const int u   = l >> 2;                    // unit (valid < 10)
  const int g   = l & 3;                     // gate 0=i 1=f 2=g 3=o
  const int uc  = (u < 10) ? u : 9;
  const bool valid = (u < 10);
  const float sc = (g == 2) ? 2.0f*LOG2E : -LOG2E;
  const int row = g*10 + uc;

  float wh[10];
#pragma unroll
  for (int m = 0; m < 10; ++m) wh[m] = valid ? Whh[row*10 + m]*sc : 0.0f;
  const float wx   = valid ? Wih[row]*sc : 0.0f;
  const float bia  = valid ? (bih[row] + bhh[row])*sc : 0.0f;
  const float actA = (g == 2) ? 1.0f : 0.0f;
  const float actB = (g == 2) ? -2.0f : 1.0f;

  float c     = valid ? c0[e*10 + uc] : 0.0f;
  float hlast = valid ? h0[e*10 + uc] : 0.0f;

  float sh0, sh1, sh2, sh3, sh4, sh5, sh6, sh7, sh8, sh9;
  {
    const int hb = __float_as_int(hlast);
    sh0 = __int_as_float(__builtin_amdgcn_readlane(hb,  0));
    sh1 = __int_as_float(__builtin_amdgcn_readlane(hb,  4));
    sh2 = __int_as_float(__builtin_amdgcn_readlane(hb,  8));
    sh3 = __int_as_float(__builtin_amdgcn_readlane(hb, 12));
    sh4 = __int_as_float(__builtin_amdgcn_readlane(hb, 16));
    sh5 = __int_as_float(__builtin_amdgcn_readlane(hb, 20));
    sh6 = __int_as_float(__builtin_amdgcn_readlane(hb, 24));
    sh7 = __int_as_float(__builtin_amdgcn_readlane(hb, 28));
    sh8 = __int_as_float(__builtin_amdgcn_readlane(hb, 32));
    sh9 = __int_as_float(__builtin_amdgcn_readlane(hb, 36));
  }

  const ushort* fB = featB + e*512;
  int vxc = (int)fB[l];            // steps 0..63 (bf16 bits, zero-extended)
  int vxn = (int)fB[64 + l];       // steps 64..127

  for (int win = 0; win < 8; ++win){
#pragma unroll 8
    for (int j = 0; j < 64; ++j){
      const float xs = __int_as_float(__builtin_amdgcn_readlane(vxc, j) << 16);
      // 4-accumulator tree: depth 3 FMA + 2 adds
      float a0 = __builtin_fmaf(wx, xs, bia);
      a0 = __builtin_fmaf(wh[0], sh0, a0);
      a0 = __builtin_fmaf(wh[1], sh1, a0);
      float a1 = wh[2]*sh2;
      a1 = __builtin_fmaf(wh[3], sh3, a1);
      a1 = __builtin_fmaf(wh[4], sh4, a1);
      float a2 = wh[5]*sh5;
      a2 = __builtin_fmaf(wh[6], sh6, a2);
      a2 = __builtin_fmaf(wh[7], sh7, a2);
      float a3 = wh[8]*sh8;
      a3 = __builtin_fmaf(wh[9], sh9, a3);
      const float acc = (a0 + a1) + (a2 + a3);
      const float rc  = rcp_(1.0f + ex2_(acc));
      const float val = __builtin_fmaf(actB, rc, actA);
      const int   vi  = __float_as_int(val);
      const float si  = __int_as_float(__builtin_amdgcn_mov_dpp(vi, 0x00, 0xF, 0xF, false));
      const float sf  = __int_as_float(__builtin_amdgcn_mov_dpp(vi, 0x55, 0xF, 0xF, false));
      const float tg  = __int_as_float(__builtin_amdgcn_mov_dpp(vi, 0xAA, 0xF, 0xF, false));
      const float so  = __int_as_float(__builtin_amdgcn_mov_dpp(vi, 0xFF, 0xF, 0xF, false));
      c = __builtin_fmaf(sf, c, si*tg);
      const float tc = __builtin_fmaf(-2.0f, rcp_(1.0f + ex2_(2.0f*LOG2E*c)), 1.0f);
      const float h  = so*tc;
      hlast = h;
      const int hbi = __float_as_int(h);
      sh0 = __int_as_float(__builtin_amdgcn_readlane(hbi,  0));
      sh1 = __int_as_float(__builtin_amdgcn_readlane(hbi,  4));
      sh2 = __int_as_float(__builtin_amdgcn_readlane(hbi,  8));
      sh3 = __int_as_float(__builtin_amdgcn_readlane(hbi, 12));
      sh4 = __int_as_float(__builtin_amdgcn_readlane(hbi, 16));
      sh5 = __int_as_float(__builtin_amdgcn_readlane(hbi, 20));
      sh6 = __int_as_float(__builtin_amdgcn_readlane(hbi, 24));
      sh7 = __int_as_float(__builtin_amdgcn_readlane(hbi, 28));
      sh8 = __int_as_float(__builtin_amdgcn_readlane(hbi, 32));
      sh9 = __int_as_float(__builtin_amdgcn_readlane(hbi, 36));
    }
    vxc = vxn;
    if (win < 6) vxn = (int)fB[(win+2)*64 + l];
  }

  // ---- log-softmax over units 0..9 ----------------------------------------
  float mx = sh0;
  mx = fmaxf(mx, sh1); mx = fmaxf(mx, sh2); mx = fmaxf(mx, sh3);
  mx = fmaxf(mx, sh4); mx = fmaxf(mx, sh5); mx = fmaxf(mx, sh6);
  mx = fmaxf(mx, sh7); mx = fmaxf(mx, sh8); mx = fmaxf(mx, sh9);
  float es = ex2_(LOG2E*(sh0 - mx));
  es += ex2_(LOG2E*(sh1 - mx)); es += ex2_(LOG2E*(sh2 - mx));
  es += ex2_(LOG2E*(sh3 - mx)); es += ex2_(LOG2E*(sh4 - mx));
  es += ex2_(LOG2E*(sh5 - mx)); es += ex2_(LOG2E*(sh6 - mx));
  es += ex2_(LOG2E*(sh7 - mx)); es += ex2_(LOG2E*(sh8 - mx));
  es += ex2_(LOG2E*(sh9 - mx));
  const float lse = LN2 * lg2_(es);
  if (valid && g == 0) out[e*10 + u] = hlast - mx - lse;
}

extern "C" void kernel_launch(void* const* d_in, const int* in_sizes, int n_in,
                              void* d_out, int out_size, void* d_ws, size_t ws_size,
                              hipStream_t stream)
{
  const float* x = (const float*)d_in[0];
  LstmArgs a;
  const int base[4] = {1, 5, 9, 13};   // lr_f, lr_b, ud_f, ud_b
  for (int d = 0; d < 4; ++d){
    a.Wih[d] = (const float*)d_in[base[d] + 0];
    a.Whh[d] = (const float*)d_in[base[d] + 1];
    a.bih[d] = (const float*)d_in[base[d] + 2];
    a.bhh[d] = (const float*)d_in[base[d] + 3];
  }
  const float* h0lr = (const float*)d_in[21];
  const float* c0lr = (const float*)d_in[22];
  const float* h0ud = (const float*)d_in[23];
  const float* c0ud = (const float*)d_in[24];
  a.h0[0] = h0lr;               a.c0[0] = c0lr;
  a.h0[1] = h0lr + 2048*128;    a.c0[1] = c0lr + 2048*128;
  a.h0[2] = h0ud;               a.c0[2] = c0ud;
  a.h0[3] = h0ud + 2048*128;    a.c0[3] = c0ud + 2048*128;

  char* ws = (char*)d_ws;
  __bf16* featB = (__bf16*)ws;                          // 2048*512*2 = 2 MiB
  bf16x8* wpack = (bf16x8*)(ws + (2u<<20));             // 40960*16 = 640 KiB
  float*  bpack = (float*)(ws + (2u<<20) + 655360u);    // 2048*4 = 8 KiB

  pack_weights<<<160, 256, 0, stream>>>(a, wpack, bpack);
  lstm4_kernel<<<256, 512, 0, stream>>>(x, a, wpack, bpack, featB);
  fc_lstm_wave<<<512, 256, 0, stream>>>((const ushort*)featB,
      (const float*)d_in[17], (const float*)d_in[18],
      (const float*)d_in[19], (const float*)d_in[20],
      (const float*)d_in[25], (const float*)d_in[26],
      (float*)d_out);
}

// Round 10
// 130.078 us; speedup vs baseline: 1.2330x; 1.0588x over previous
//
#include <hip/hip_runtime.h>
#include <hip/hip_bf16.h>

typedef __bf16   bf16x8 __attribute__((ext_vector_type(8)));
typedef float    f32x4  __attribute__((ext_vector_type(4)));
typedef _Float16 h16x2  __attribute__((ext_vector_type(2)));

#define LOG2E 1.4426950408889634f
#define LN2   0.6931471805599453f

__device__ __forceinline__ float rcp_(float x){
#if __has_builtin(__builtin_amdgcn_rcpf)
  return __builtin_amdgcn_rcpf(x);
#else
  return 1.0f / x;
#endif
}
__device__ __forceinline__ float ex2_(float x){
#if __has_builtin(__builtin_amdgcn_exp2f)
  return __builtin_amdgcn_exp2f(x);
#else
  return exp2f(x);
#endif
}
__device__ __forceinline__ float lg2_(float x){
#if __has_builtin(__builtin_amdgcn_logf)
  return __builtin_amdgcn_logf(x);
#else
  return log2f(x);
#endif
}

// pack two f32 -> f16x2 bit-pattern (int)
__device__ __forceinline__ int pkrtz_(float a, float b){
  auto v = __builtin_amdgcn_cvt_pkrtz(a, b);
  int r; __builtin_memcpy(&r, &v, 4); return r;
}
__device__ __forceinline__ h16x2 as_h2_(int x){
  h16x2 r; __builtin_memcpy(&r, &x, 4); return r;
}

#if __has_builtin(__builtin_amdgcn_fdot2)
__device__ __forceinline__ float fdot2_(int w, int h, float a){
  return __builtin_amdgcn_fdot2(as_h2_(w), as_h2_(h), a, false);
}
#else
__device__ __forceinline__ float fdot2_(int w, int h, float a){
  h16x2 wv = as_h2_(w), hv = as_h2_(h);
  return a + (float)wv[0]*(float)hv[0] + (float)wv[1]*(float)hv[1];
}
#endif

struct LstmArgs {
  const float* Wih[4]; const float* Whh[4];
  const float* bih[4]; const float* bhh[4];
  const float* h0[4];  const float* c0[4];
};

// ---------------------------------------------------------------------------
// pack_weights: fragment-lane-ordered, pre-scaled bf16x8 weight blobs +
// pre-scaled biases. wpack[((d*8+w)*4+g)*5+kk][lane] ; bpack[d*512 + grow]
// ---------------------------------------------------------------------------
__global__ void pack_weights(LstmArgs args, bf16x8* __restrict__ wpack,
                             float* __restrict__ bpack)
{
  const int idx = blockIdx.x*256 + threadIdx.x;      // 40960 total
  if (idx >= 4*8*4*5*64) return;
  const int lane = idx & 63;
  int r = idx >> 6;
  const int kk = r % 5; r /= 5;
  const int g  = r & 3; r >>= 2;
  const int w  = r & 7;
  const int d  = r >> 3;
  const int lc = lane & 15, lr4 = lane >> 4;
  const int grow = g*128 + w*16 + lc;
  const float sc = (g == 2) ? 2.0f*LOG2E : -LOG2E;

  bf16x8 v;
  if (kk < 4){
    const float* p = args.Whh[d] + grow*128 + kk*32 + lr4*8;
#pragma unroll
    for (int j = 0; j < 8; ++j) v[j] = (__bf16)(p[j] * sc);
  } else {
#pragma unroll
    for (int j = 0; j < 8; ++j){
      const int xi = lr4*8 + j;
      v[j] = (xi < 28) ? (__bf16)(args.Wih[d][grow*28 + xi] * sc) : (__bf16)0.0f;
    }
  }
  wpack[idx] = v;
  if (kk == 0 && lr4 == 0)
    bpack[d*512 + grow] = (args.bih[d][grow] + args.bhh[d][grow]) * sc;
}

// ---------------------------------------------------------------------------
// Kernel A: 4 dirs x 64 batch-blocks of 32 rows, 8 waves (512 thr), 256
// blocks = 1/CU. Weights via coalesced wpack loads (regs). x staged once.
// Double-buffered hcat -> ONE barrier per step. Fused-rcp activations:
// 5 ex2 + 3 rcp per cell.
// ---------------------------------------------------------------------------
__global__ __launch_bounds__(512, 2) void lstm4_kernel(const float* __restrict__ x,
                                                       LstmArgs args,
                                                       const bf16x8* __restrict__ wpack,
                                                       const float* __restrict__ bpack,
                                                       __bf16* __restrict__ featB)
{
  const int dir = blockIdx.x >> 6;          // 0=lr_f 1=lr_b 2=ud_f 3=ud_b
  const int b0  = (blockIdx.x & 63) * 32;
  const int tid = threadIdx.x;
  const int w   = tid >> 6;                 // wave 0..7
  const int l   = tid & 63;
  const int lc  = l & 15;
  const int lr4 = l >> 4;

  const float* __restrict__ h0 = args.h0[dir];
  const float* __restrict__ c0 = args.c0[dir];
  const int rev = dir & 1;
  const bool lrdir = (dir < 2);

  __shared__ __align__(16) __bf16 hcat[2][32 * 168];     // 21 KiB
  __shared__ __align__(16) __bf16 xstage[28 * 32 * 40];  // 70 KiB

  // ---- B fragments: coalesced 16B loads from wpack ------------------------
  bf16x8 bfr[4][5];
  float  bias[4];
  {
    const bf16x8* wp = wpack + (dir*8 + w)*4*5*64;
#pragma unroll
    for (int g = 0; g < 4; ++g){
#pragma unroll
      for (int kk = 0; kk < 5; ++kk)
        bfr[g][kk] = wp[(g*5 + kk)*64 + l];
      bias[g] = bpack[dir*512 + g*128 + w*16 + lc];
    }
  }

  // ---- stage x tile once, float4 global loads ------------------------------
  for (int idx = tid; idx < 32*196; idx += 512){   // 196 = 28*7 float4 per row
    const int row = idx / 196;
    const int rem = idx - row*196;
    if (lrdir){
      const int t = rem / 7, jg = rem - 7*t;
      const float4 v = *(const float4*)&x[(b0+row)*784 + t*28 + jg*4];
      __bf16* dst = &xstage[(t*32 + row)*40 + jg*4];
      dst[0]=(__bf16)v.x; dst[1]=(__bf16)v.y; dst[2]=(__bf16)v.z; dst[3]=(__bf16)v.w;
    } else {
      const int j = rem / 7, tg = rem - 7*j;
      const float4 v = *(const float4*)&x[(b0+row)*784 + j*28 + tg*4];
      xstage[((tg*4+0)*32 + row)*40 + j] = (__bf16)v.x;
      xstage[((tg*4+1)*32 + row)*40 + j] = (__bf16)v.y;
      xstage[((tg*4+2)*32 + row)*40 + j] = (__bf16)v.z;
      xstage[((tg*4+3)*32 + row)*40 + j] = (__bf16)v.w;
    }
  }
  for (int idx = tid; idx < 28*32; idx += 512){    // zero K-pad cols 28..31
    const int t = idx >> 5, row = idx & 31;
    __bf16* p = &xstage[(t*32 + row)*40 + 28];
    p[0] = p[1] = p[2] = p[3] = (__bf16)0.0f;
  }

  // ---- initial state -------------------------------------------------------
  float cst[2][4];
#pragma unroll
  for (int m = 0; m < 2; ++m)
#pragma unroll
  for (int r = 0; r < 4; ++r){
    const int row = 16*m + 4*lr4 + r;
    const int col = w*16 + lc;
    cst[m][r] = c0[(b0+row)*128 + col];
    hcat[0][row*168 + col] = (__bf16)h0[(b0+row)*128 + col];
  }
  __syncthreads();

  // ---- 28 sequential steps, ONE barrier each -------------------------------
  int cur = 0;
  for (int s = 0; s < 28; ++s){
    const int t = rev ? (27 - s) : s;
    const int nxt = cur ^ 1;

    f32x4 acc[2][4];
#pragma unroll
    for (int m = 0; m < 2; ++m)
#pragma unroll
    for (int g = 0; g < 4; ++g){
      f32x4 bv = {bias[g], bias[g], bias[g], bias[g]};
      acc[m][g] = bv;
    }
#pragma unroll
    for (int m = 0; m < 2; ++m){
#pragma unroll
      for (int kk = 0; kk < 5; ++kk){
        const bf16x8 a = (kk < 4)
          ? *(const bf16x8*)&hcat[cur][(16*m + lc)*168 + kk*32 + lr4*8]
          : *(const bf16x8*)&xstage[(t*32 + 16*m + lc)*40 + lr4*8];
#pragma unroll
        for (int g = 0; g < 4; ++g)
          acc[m][g] = __builtin_amdgcn_mfma_f32_16x16x32_bf16(a, bfr[g][kk], acc[m][g], 0, 0, 0);
      }
    }

    // fused-rcp activations: 5 ex2 + 3 rcp per cell
#pragma unroll
    for (int m = 0; m < 2; ++m)
#pragma unroll
    for (int r = 0; r < 4; ++r){
      const float Ei = ex2_(acc[m][0][r]);   // e^{-i}
      const float Ef = ex2_(acc[m][1][r]);   // e^{-f}
      const float Eg = ex2_(acc[m][2][r]);   // e^{2g}
      const float Eo = ex2_(acc[m][3][r]);   // e^{-o}
      const float rf  = rcp_(1.0f + Ef);
      const float rig = rcp_((1.0f + Ei)*(1.0f + Eg));
      const float cc  = rf*cst[m][r] + (Eg - 1.0f)*rig;
      cst[m][r] = cc;
      const float Ec  = ex2_(2.0f*LOG2E*cc); // e^{2c}
      const float roc = rcp_((1.0f + Eo)*(1.0f + Ec));
      const float hv  = (Ec - 1.0f)*roc;     // sig(o)*tanh(c)
      hcat[nxt][(16*m + 4*lr4 + r)*168 + w*16 + lc] = (__bf16)hv;
    }
    __syncthreads();
    cur = nxt;
  }

  // ---- epilogue: final h (in hcat[cur]) -> featB[batch][512], coalesced ----
  {
    const int row = tid >> 4;      // 0..31
    const int cg  = tid & 15;      // 0..15
    const bf16x8 hv = *(const bf16x8*)&hcat[cur][row*168 + cg*8];
    *(bf16x8*)&featB[(b0+row)*512 + dir*128 + cg*8] = hv;
  }
}

// ---------------------------------------------------------------------------
// Kernel B: fc LSTM, one wave per batch element (2048 waves, 2/SIMD).
// Lanes = gate-rows 4u+g (40 active). Issue-bound -> minimize instr/step:
// h packed to f16 pairs ENTIRELY in VALU domain (mov_dpp row_shl:4 brings
// h[u+1] to lane 4u; cvt_pkrtz; 5 readlanes) and dot via 5 fdot2.
// quad_perm DPP gathers i/f/g/o. No LDS, no DS ops, no barriers.
// ---------------------------------------------------------------------------
__global__ __launch_bounds__(256) void fc_lstm_wave(const ushort* __restrict__ featB,
                                                    const float* __restrict__ Wih,
                                                    const float* __restrict__ Whh,
                                                    const float* __restrict__ bih,
                                                    const float* __restrict__ bhh,
                                                    const float* __restrict__ h0,
                                                    const float* __restrict__ c0,
                                                    float* __restrict__ out)
{
  const int tid = threadIdx.x;
  const int l   = tid & 63;
  const int e   = blockIdx.x*4 + (tid >> 6);
  const int u   = l >> 2;                    // unit (valid < 10)
  const int g   = l & 3;                     // gate 0=i 1=f 2=g 3=o
  const int uc  = (u < 10) ? u : 9;
  const bool valid = (u < 10);
  const float sc = (g == 2) ? 2.0f*LOG2E : -LOG2E;
  const int row = g*10 + uc;

  // weights packed f16 pairs: wh2[m] = (W[row][2m], W[row][2m+1]) * sc
  int wh2[5];
#pragma unroll
  for (int m = 0; m < 5; ++m){
    const float w0 = valid ? Whh[row*10 + 2*m]   * sc : 0.0f;
    const float w1 = valid ? Whh[row*10 + 2*m+1] * sc : 0.0f;
    wh2[m] = pkrtz_(w0, w1);
  }
  const float wx   = valid ? Wih[row]*sc : 0.0f;
  const float bia  = valid ? (bih[row] + bhh[row])*sc : 0.0f;
  const float actA = (g == 2) ? 1.0f : 0.0f;
  const float actB = (g == 2) ? -2.0f : 1.0f;

  float c     = valid ? c0[e*10 + uc] : 0.0f;
  float hlast = valid ? h0[e*10 + uc] : 0.0f;

  // h-pair pack: lane 4u gets h[u+1] via DPP row_shl:4 (0x104); pairs read
  // from lanes 0,8,16,24,32 -> (h0,h1),(h2,h3),(h4,h5),(h6,h7),(h8,h9).
  int hp0, hp1, hp2, hp3, hp4;
  {
    const int hn = __builtin_amdgcn_mov_dpp(__float_as_int(hlast), 0x104, 0xF, 0xF, false);
    const int hpi = pkrtz_(hlast, __int_as_float(hn));
    hp0 = __builtin_amdgcn_readlane(hpi,  0);
    hp1 = __builtin_amdgcn_readlane(hpi,  8);
    hp2 = __builtin_amdgcn_readlane(hpi, 16);
    hp3 = __builtin_amdgcn_readlane(hpi, 24);
    hp4 = __builtin_amdgcn_readlane(hpi, 32);
  }

  const ushort* fB = featB + e*512;
  int vxc = (int)fB[l];            // steps 0..63 (bf16 bits, zero-extended)
  int vxn = (int)fB[64 + l];       // steps 64..127

  for (int win = 0; win < 8; ++win){
#pragma unroll 8
    for (int j = 0; j < 64; ++j){
      const float xs = __int_as_float(__builtin_amdgcn_readlane(vxc, j) << 16);
      // dot: 1 fma + 5 fdot2 (2 accumulators) + 1 add
      float a0 = __builtin_fmaf(wx, xs, bia);
      a0 = fdot2_(wh2[0], hp0, a0);
      float a1 = fdot2_(wh2[1], hp1, 0.0f);
      a0 = fdot2_(wh2[2], hp2, a0);
      a1 = fdot2_(wh2[3], hp3, a1);
      a0 = fdot2_(wh2[4], hp4, a0);
      const float acc = a0 + a1;
      const float rc  = rcp_(1.0f + ex2_(acc));
      const float val = __builtin_fmaf(actB, rc, actA);
      const int   vi  = __float_as_int(val);
      const float si  = __int_as_float(__builtin_amdgcn_mov_dpp(vi, 0x00, 0xF, 0xF, false));
      const float sf  = __int_as_float(__builtin_amdgcn_mov_dpp(vi, 0x55, 0xF, 0xF, false));
      const float tg  = __int_as_float(__builtin_amdgcn_mov_dpp(vi, 0xAA, 0xF, 0xF, false));
      const float so  = __int_as_float(__builtin_amdgcn_mov_dpp(vi, 0xFF, 0xF, 0xF, false));
      c = __builtin_fmaf(sf, c, si*tg);
      const float tc = __builtin_fmaf(-2.0f, rcp_(1.0f + ex2_(2.0f*LOG2E*c)), 1.0f);
      const float h  = so*tc;
      hlast = h;
      const int hn  = __builtin_amdgcn_mov_dpp(__float_as_int(h), 0x104, 0xF, 0xF, false);
      const int hpi = pkrtz_(h, __int_as_float(hn));
      hp0 = __builtin_amdgcn_readlane(hpi,  0);
      hp1 = __builtin_amdgcn_readlane(hpi,  8);
      hp2 = __builtin_amdgcn_readlane(hpi, 16);
      hp3 = __builtin_amdgcn_readlane(hpi, 24);
      hp4 = __builtin_amdgcn_readlane(hpi, 32);
    }
    vxc = vxn;
    if (win < 6) vxn = (int)fB[(win+2)*64 + l];
  }

  // ---- log-softmax over units 0..9 (exact f32 h via plain readlanes) -------
  const int hb = __float_as_int(hlast);
  float sh[10];
#pragma unroll
  for (int m = 0; m < 10; ++m)
    sh[m] = __int_as_float(__builtin_amdgcn_readlane(hb, 4*m));
  float mx = sh[0];
#pragma unroll
  for (int m = 1; m < 10; ++m) mx = fmaxf(mx, sh[m]);
  float es = 0.0f;
#pragma unroll
  for (int m = 0; m < 10; ++m) es += ex2_(LOG2E*(sh[m] - mx));
  const float lse = LN2 * lg2_(es);
  if (valid && g == 0) out[e*10 + u] = hlast - mx - lse;
}

extern "C" void kernel_launch(void* const* d_in, const int* in_sizes, int n_in,
                              void* d_out, int out_size, void* d_ws, size_t ws_size,
                              hipStream_t stream)
{
  const float* x = (const float*)d_in[0];
  LstmArgs a;
  const int base[4] = {1, 5, 9, 13};   // lr_f, lr_b, ud_f, ud_b
  for (int d = 0; d < 4; ++d){
    a.Wih[d] = (const float*)d_in[base[d] + 0];
    a.Whh[d] = (const float*)d_in[base[d] + 1];
    a.bih[d] = (const float*)d_in[base[d] + 2];
    a.bhh[d] = (const float*)d_in[base[d] + 3];
  }
  const float* h0lr = (const float*)d_in[21];
  const float* c0lr = (const float*)d_in[22];
  const float* h0ud = (const float*)d_in[23];
  const float* c0ud = (const float*)d_in[24];
  a.h0[0] = h0lr;               a.c0[0] = c0lr;
  a.h0[1] = h0lr + 2048*128;    a.c0[1] = c0lr + 2048*128;
  a.h0[2] = h0ud;               a.c0[2] = c0ud;
  a.h0[3] = h0ud + 2048*128;    a.c0[3] = c0ud + 2048*128;

  char* ws = (char*)d_ws;
  __bf16* featB = (__bf16*)ws;                          // 2048*512*2 = 2 MiB
  bf16x8* wpack = (bf16x8*)(ws + (2u<<20));             // 40960*16 = 640 KiB
  float*  bpack = (float*)(ws + (2u<<20) + 655360u);    // 2048*4 = 8 KiB

  pack_weights<<<160, 256, 0, stream>>>(a, wpack, bpack);
  lstm4_kernel<<<256, 512, 0, stream>>>(x, a, wpack, bpack, featB);
  fc_lstm_wave<<<512, 256, 0, stream>>>((const ushort*)featB,
      (const float*)d_in[17], (const float*)d_in[18],
      (const float*)d_in[19], (const float*)d_in[20],
      (const float*)d_in[25], (const float*)d_in[26],
      (float*)d_out);
}

// Round 11
// 126.651 us; speedup vs baseline: 1.2664x; 1.0271x over previous
//
#include <hip/hip_runtime.h>
#include <hip/hip_bf16.h>

typedef __bf16   bf16x8 __attribute__((ext_vector_type(8)));
typedef float    f32x4  __attribute__((ext_vector_type(4)));
typedef _Float16 h16x2  __attribute__((ext_vector_type(2)));

#define LOG2E 1.4426950408889634f
#define LN2   0.6931471805599453f

__device__ __forceinline__ float rcp_(float x){
#if __has_builtin(__builtin_amdgcn_rcpf)
  return __builtin_amdgcn_rcpf(x);
#else
  return 1.0f / x;
#endif
}
__device__ __forceinline__ float ex2_(float x){
#if __has_builtin(__builtin_amdgcn_exp2f)
  return __builtin_amdgcn_exp2f(x);
#else
  return exp2f(x);
#endif
}
__device__ __forceinline__ float lg2_(float x){
#if __has_builtin(__builtin_amdgcn_logf)
  return __builtin_amdgcn_logf(x);
#else
  return log2f(x);
#endif
}

// pack two f32 -> f16x2 bit-pattern (int)
__device__ __forceinline__ int pkrtz_(float a, float b){
  auto v = __builtin_amdgcn_cvt_pkrtz(a, b);
  int r; __builtin_memcpy(&r, &v, 4); return r;
}
__device__ __forceinline__ h16x2 as_h2_(int x){
  h16x2 r; __builtin_memcpy(&r, &x, 4); return r;
}

#if __has_builtin(__builtin_amdgcn_fdot2)
__device__ __forceinline__ float fdot2_(int w, int h, float a){
  return __builtin_amdgcn_fdot2(as_h2_(w), as_h2_(h), a, false);
}
#else
__device__ __forceinline__ float fdot2_(int w, int h, float a){
  h16x2 wv = as_h2_(w), hv = as_h2_(h);
  return a + (float)wv[0]*(float)hv[0] + (float)wv[1]*(float)hv[1];
}
#endif

struct LstmArgs {
  const float* Wih[4]; const float* Whh[4];
  const float* bih[4]; const float* bhh[4];
  const float* h0[4];  const float* c0[4];
};

// ---------------------------------------------------------------------------
// pack_weights: fragment-lane-ordered, pre-scaled bf16x8 weight blobs +
// pre-scaled biases. wpack[((d*8+w)*4+g)*5+kk][lane] ; bpack[d*512 + grow]
// ---------------------------------------------------------------------------
__global__ void pack_weights(LstmArgs args, bf16x8* __restrict__ wpack,
                             float* __restrict__ bpack)
{
  const int idx = blockIdx.x*256 + threadIdx.x;      // 40960 total
  if (idx >= 4*8*4*5*64) return;
  const int lane = idx & 63;
  int r = idx >> 6;
  const int kk = r % 5; r /= 5;
  const int g  = r & 3; r >>= 2;
  const int w  = r & 7;
  const int d  = r >> 3;
  const int lc = lane & 15, lr4 = lane >> 4;
  const int grow = g*128 + w*16 + lc;
  const float sc = (g == 2) ? 2.0f*LOG2E : -LOG2E;

  bf16x8 v;
  if (kk < 4){
    const float* p = args.Whh[d] + grow*128 + kk*32 + lr4*8;
#pragma unroll
    for (int j = 0; j < 8; ++j) v[j] = (__bf16)(p[j] * sc);
  } else {
#pragma unroll
    for (int j = 0; j < 8; ++j){
      const int xi = lr4*8 + j;
      v[j] = (xi < 28) ? (__bf16)(args.Wih[d][grow*28 + xi] * sc) : (__bf16)0.0f;
    }
  }
  wpack[idx] = v;
  if (kk == 0 && lr4 == 0)
    bpack[d*512 + grow] = (args.bih[d][grow] + args.bhh[d][grow]) * sc;
}

// ---------------------------------------------------------------------------
// Kernel A: 4 dirs x 64 batch-blocks of 32 rows, 8 waves (512 thr), 256
// blocks = 1/CU. Weights via coalesced wpack loads (regs). x staged once.
// Double-buffered hcat -> ONE barrier per step. Fused-rcp activations:
// 5 ex2 + 3 rcp per cell.
// ---------------------------------------------------------------------------
__global__ __launch_bounds__(512, 2) void lstm4_kernel(const float* __restrict__ x,
                                                       LstmArgs args,
                                                       const bf16x8* __restrict__ wpack,
                                                       const float* __restrict__ bpack,
                                                       __bf16* __restrict__ featB)
{
  const int dir = blockIdx.x >> 6;          // 0=lr_f 1=lr_b 2=ud_f 3=ud_b
  const int b0  = (blockIdx.x & 63) * 32;
  const int tid = threadIdx.x;
  const int w   = tid >> 6;                 // wave 0..7
  const int l   = tid & 63;
  const int lc  = l & 15;
  const int lr4 = l >> 4;

  const float* __restrict__ h0 = args.h0[dir];
  const float* __restrict__ c0 = args.c0[dir];
  const int rev = dir & 1;
  const bool lrdir = (dir < 2);

  __shared__ __align__(16) __bf16 hcat[2][32 * 168];     // 21 KiB
  __shared__ __align__(16) __bf16 xstage[28 * 32 * 40];  // 70 KiB

  // ---- B fragments: coalesced 16B loads from wpack ------------------------
  bf16x8 bfr[4][5];
  float  bias[4];
  {
    const bf16x8* wp = wpack + (dir*8 + w)*4*5*64;
#pragma unroll
    for (int g = 0; g < 4; ++g){
#pragma unroll
      for (int kk = 0; kk < 5; ++kk)
        bfr[g][kk] = wp[(g*5 + kk)*64 + l];
      bias[g] = bpack[dir*512 + g*128 + w*16 + lc];
    }
  }

  // ---- stage x tile once, float4 global loads ------------------------------
  for (int idx = tid; idx < 32*196; idx += 512){   // 196 = 28*7 float4 per row
    const int row = idx / 196;
    const int rem = idx - row*196;
    if (lrdir){
      const int t = rem / 7, jg = rem - 7*t;
      const float4 v = *(const float4*)&x[(b0+row)*784 + t*28 + jg*4];
      __bf16* dst = &xstage[(t*32 + row)*40 + jg*4];
      dst[0]=(__bf16)v.x; dst[1]=(__bf16)v.y; dst[2]=(__bf16)v.z; dst[3]=(__bf16)v.w;
    } else {
      const int j = rem / 7, tg = rem - 7*j;
      const float4 v = *(const float4*)&x[(b0+row)*784 + j*28 + tg*4];
      xstage[((tg*4+0)*32 + row)*40 + j] = (__bf16)v.x;
      xstage[((tg*4+1)*32 + row)*40 + j] = (__bf16)v.y;
      xstage[((tg*4+2)*32 + row)*40 + j] = (__bf16)v.z;
      xstage[((tg*4+3)*32 + row)*40 + j] = (__bf16)v.w;
    }
  }
  for (int idx = tid; idx < 28*32; idx += 512){    // zero K-pad cols 28..31
    const int t = idx >> 5, row = idx & 31;
    __bf16* p = &xstage[(t*32 + row)*40 + 28];
    p[0] = p[1] = p[2] = p[3] = (__bf16)0.0f;
  }

  // ---- initial state -------------------------------------------------------
  float cst[2][4];
#pragma unroll
  for (int m = 0; m < 2; ++m)
#pragma unroll
  for (int r = 0; r < 4; ++r){
    const int row = 16*m + 4*lr4 + r;
    const int col = w*16 + lc;
    cst[m][r] = c0[(b0+row)*128 + col];
    hcat[0][row*168 + col] = (__bf16)h0[(b0+row)*128 + col];
  }
  __syncthreads();

  // ---- 28 sequential steps, ONE barrier each -------------------------------
  int cur = 0;
  for (int s = 0; s < 28; ++s){
    const int t = rev ? (27 - s) : s;
    const int nxt = cur ^ 1;

    f32x4 acc[2][4];
#pragma unroll
    for (int m = 0; m < 2; ++m)
#pragma unroll
    for (int g = 0; g < 4; ++g){
      f32x4 bv = {bias[g], bias[g], bias[g], bias[g]};
      acc[m][g] = bv;
    }
#pragma unroll
    for (int m = 0; m < 2; ++m){
#pragma unroll
      for (int kk = 0; kk < 5; ++kk){
        const bf16x8 a = (kk < 4)
          ? *(const bf16x8*)&hcat[cur][(16*m + lc)*168 + kk*32 + lr4*8]
          : *(const bf16x8*)&xstage[(t*32 + 16*m + lc)*40 + lr4*8];
#pragma unroll
        for (int g = 0; g < 4; ++g)
          acc[m][g] = __builtin_amdgcn_mfma_f32_16x16x32_bf16(a, bfr[g][kk], acc[m][g], 0, 0, 0);
      }
    }

    // fused-rcp activations: 5 ex2 + 3 rcp per cell
#pragma unroll
    for (int m = 0; m < 2; ++m)
#pragma unroll
    for (int r = 0; r < 4; ++r){
      const float Ei = ex2_(acc[m][0][r]);   // e^{-i}
      const float Ef = ex2_(acc[m][1][r]);   // e^{-f}
      const float Eg = ex2_(acc[m][2][r]);   // e^{2g}
      const float Eo = ex2_(acc[m][3][r]);   // e^{-o}
      const float rf  = rcp_(1.0f + Ef);
      const float rig = rcp_((1.0f + Ei)*(1.0f + Eg));
      const float cc  = rf*cst[m][r] + (Eg - 1.0f)*rig;
      cst[m][r] = cc;
      const float Ec  = ex2_(2.0f*LOG2E*cc); // e^{2c}
      const float roc = rcp_((1.0f + Eo)*(1.0f + Ec));
      const float hv  = (Ec - 1.0f)*roc;     // sig(o)*tanh(c)
      hcat[nxt][(16*m + 4*lr4 + r)*168 + w*16 + lc] = (__bf16)hv;
    }
    __syncthreads();
    cur = nxt;
  }

  // ---- epilogue: final h (in hcat[cur]) -> featB[batch][512], coalesced ----
  {
    const int row = tid >> 4;      // 0..31
    const int cg  = tid & 15;      // 0..15
    const bf16x8 hv = *(const bf16x8*)&hcat[cur][row*168 + cg*8];
    *(bf16x8*)&featB[(b0+row)*512 + dir*128 + cg*8] = hv;
  }
}

// ---------------------------------------------------------------------------
// Kernel B: fc LSTM, one wave per batch element (2048 waves, 2/SIMD).
// Lanes = gate-rows 4u+g (40 active). Issue-bound -> minimize VALU/step:
// (1) xt from SCALAR loads: featB row is wave-uniform; readfirstlane-pinned
//     pointer -> s_load into SGPR window buffers; per-step extract is SALU.
// (2) c/h kept valid only on g==0 lanes -> gather only sf/tg/so (3 mov_dpp,
//     each single-use so GCNDPPCombine can fuse into mul/fmac).
// (3) h-dot via 5 fdot2 on f16 pairs packed in VALU domain (dpp + pkrtz).
// ---------------------------------------------------------------------------
__global__ __launch_bounds__(256) void fc_lstm_wave(const ushort* __restrict__ featB,
                                                    const float* __restrict__ Wih,
                                                    const float* __restrict__ Whh,
                                                    const float* __restrict__ bih,
                                                    const float* __restrict__ bhh,
                                                    const float* __restrict__ h0,
                                                    const float* __restrict__ c0,
                                                    float* __restrict__ out)
{
  const int tid = threadIdx.x;
  const int l   = tid & 63;
  const int e   = blockIdx.x*4 + (tid >> 6);
  const int u   = l >> 2;                    // unit (valid < 10)
  const int g   = l & 3;                     // gate 0=i 1=f 2=g 3=o
  const int uc  = (u < 10) ? u : 9;
  const bool valid = (u < 10);
  const float sc = (g == 2) ? 2.0f*LOG2E : -LOG2E;
  const int row = g*10 + uc;

  // weights packed f16 pairs: wh2[m] = (W[row][2m], W[row][2m+1]) * sc
  int wh2[5];
#pragma unroll
  for (int m = 0; m < 5; ++m){
    const float w0 = valid ? Whh[row*10 + 2*m]   * sc : 0.0f;
    const float w1 = valid ? Whh[row*10 + 2*m+1] * sc : 0.0f;
    wh2[m] = pkrtz_(w0, w1);
  }
  const float wx   = valid ? Wih[row]*sc : 0.0f;
  const float bia  = valid ? (bih[row] + bhh[row])*sc : 0.0f;
  const float actA = (g == 2) ? 1.0f : 0.0f;
  const float actB = (g == 2) ? -2.0f : 1.0f;

  float c     = valid ? c0[e*10 + uc] : 0.0f;
  float hlast = valid ? h0[e*10 + uc] : 0.0f;

  // h-pair pack: lane 4u gets h[u+1] via DPP row_shl:4 (0x104); pairs read
  // from lanes 0,8,16,24,32 -> (h0,h1),(h2,h3),(h4,h5),(h6,h7),(h8,h9).
  int hp0, hp1, hp2, hp3, hp4;
  {
    const int hn = __builtin_amdgcn_mov_dpp(__float_as_int(hlast), 0x104, 0xF, 0xF, false);
    const int hpi = pkrtz_(hlast, __int_as_float(hn));
    hp0 = __builtin_amdgcn_readlane(hpi,  0);
    hp1 = __builtin_amdgcn_readlane(hpi,  8);
    hp2 = __builtin_amdgcn_readlane(hpi, 16);
    hp3 = __builtin_amdgcn_readlane(hpi, 24);
    hp4 = __builtin_amdgcn_readlane(hpi, 32);
  }

  // ---- scalarized featB pointer (wave-uniform) -> s_load windows -----------
  const uint4* fBs;
  {
    unsigned long long a = (unsigned long long)(uintptr_t)(featB + (size_t)e*512);
    unsigned lo = (unsigned)__builtin_amdgcn_readfirstlane((int)(a & 0xffffffffu));
    unsigned hi = (unsigned)__builtin_amdgcn_readfirstlane((int)(a >> 32));
    fBs = (const uint4*)(uintptr_t)(((unsigned long long)hi << 32) | lo);
  }

  unsigned int cur[8][4], nxt[8][4];   // two 64-step windows (bf16 pairs)
#pragma unroll
  for (int k = 0; k < 8; ++k){
    const uint4 q0 = fBs[k];
    cur[k][0]=q0.x; cur[k][1]=q0.y; cur[k][2]=q0.z; cur[k][3]=q0.w;
    const uint4 q1 = fBs[8 + k];
    nxt[k][0]=q1.x; nxt[k][1]=q1.y; nxt[k][2]=q1.z; nxt[k][3]=q1.w;
  }

  for (int win = 0; win < 8; ++win){
#pragma unroll
    for (int blk = 0; blk < 8; ++blk){
#pragma unroll
      for (int jj = 0; jj < 8; ++jj){
        const unsigned d  = cur[blk][jj >> 1];
        const unsigned xb = (jj & 1) ? (d & 0xffff0000u) : (d << 16);
        const float xs = __int_as_float((int)xb);
        // dot: 1 fma + 5 fdot2 (2 accumulators) + 1 add
        float a0 = __builtin_fmaf(wx, xs, bia);
        a0 = fdot2_(wh2[0], hp0, a0);
        float a1 = fdot2_(wh2[1], hp1, 0.0f);
        a0 = fdot2_(wh2[2], hp2, a0);
        a1 = fdot2_(wh2[3], hp3, a1);
        a0 = fdot2_(wh2[4], hp4, a0);
        const float acc = a0 + a1;
        const float rc  = rcp_(1.0f + ex2_(acc));
        const float val = __builtin_fmaf(actB, rc, actA);
        const int   vi  = __float_as_int(val);
        // gather only sf/tg/so (c,h valid on g==0 lanes only; val there = si)
        const float tg  = __int_as_float(__builtin_amdgcn_mov_dpp(vi, 0xAA, 0xF, 0xF, false));
        const float sf  = __int_as_float(__builtin_amdgcn_mov_dpp(vi, 0x55, 0xF, 0xF, false));
        const float so  = __int_as_float(__builtin_amdgcn_mov_dpp(vi, 0xFF, 0xF, 0xF, false));
        c = __builtin_fmaf(sf, c, val*tg);
        const float tc = __builtin_fmaf(-2.0f, rcp_(1.0f + ex2_(2.0f*LOG2E*c)), 1.0f);
        const float h  = so*tc;
        hlast = h;
        const int hn  = __builtin_amdgcn_mov_dpp(__float_as_int(h), 0x104, 0xF, 0xF, false);
        const int hpi = pkrtz_(h, __int_as_float(hn));
        hp0 = __builtin_amdgcn_readlane(hpi,  0);
        hp1 = __builtin_amdgcn_readlane(hpi,  8);
        hp2 = __builtin_amdgcn_readlane(hpi, 16);
        hp3 = __builtin_amdgcn_readlane(hpi, 24);
        hp4 = __builtin_amdgcn_readlane(hpi, 32);
      }
    }
#pragma unroll
    for (int k = 0; k < 8; ++k){
      cur[k][0]=nxt[k][0]; cur[k][1]=nxt[k][1];
      cur[k][2]=nxt[k][2]; cur[k][3]=nxt[k][3];
    }
    if (win < 6){
#pragma unroll
      for (int k = 0; k < 8; ++k){
        const uint4 q = fBs[(win + 2)*8 + k];
        nxt[k][0]=q.x; nxt[k][1]=q.y; nxt[k][2]=q.z; nxt[k][3]=q.w;
      }
    }
  }

  // ---- log-softmax over units 0..9 (h valid on g==0 lanes) ------------------
  const int hb = __float_as_int(hlast);
  float sh[10];
#pragma unroll
  for (int m = 0; m < 10; ++m)
    sh[m] = __int_as_float(__builtin_amdgcn_readlane(hb, 4*m));
  float mx = sh[0];
#pragma unroll
  for (int m = 1; m < 10; ++m) mx = fmaxf(mx, sh[m]);
  float es = 0.0f;
#pragma unroll
  for (int m = 0; m < 10; ++m) es += ex2_(LOG2E*(sh[m] - mx));
  const float lse = LN2 * lg2_(es);
  if (valid && g == 0) out[e*10 + u] = hlast - mx - lse;
}

extern "C" void kernel_launch(void* const* d_in, const int* in_sizes, int n_in,
                              void* d_out, int out_size, void* d_ws, size_t ws_size,
                              hipStream_t stream)
{
  const float* x = (const float*)d_in[0];
  LstmArgs a;
  const int base[4] = {1, 5, 9, 13};   // lr_f, lr_b, ud_f, ud_b
  for (int d = 0; d < 4; ++d){
    a.Wih[d] = (const float*)d_in[base[d] + 0];
    a.Whh[d] = (const float*)d_in[base[d] + 1];
    a.bih[d] = (const float*)d_in[base[d] + 2];
    a.bhh[d] = (const float*)d_in[base[d] + 3];
  }
  const float* h0lr = (const float*)d_in[21];
  const float* c0lr = (const float*)d_in[22];
  const float* h0ud = (const float*)d_in[23];
  const float* c0ud = (const float*)d_in[24];
  a.h0[0] = h0lr;               a.c0[0] = c0lr;
  a.h0[1] = h0lr + 2048*128;    a.c0[1] = c0lr + 2048*128;
  a.h0[2] = h0ud;               a.c0[2] = c0ud;
  a.h0[3] = h0ud + 2048*128;    a.c0[3] = c0ud + 2048*128;

  char* ws = (char*)d_ws;
  __bf16* featB = (__bf16*)ws;                          // 2048*512*2 = 2 MiB
  bf16x8* wpack = (bf16x8*)(ws + (2u<<20));             // 40960*16 = 640 KiB
  float*  bpack = (float*)(ws + (2u<<20) + 655360u);    // 2048*4 = 8 KiB

  pack_weights<<<160, 256, 0, stream>>>(a, wpack, bpack);
  lstm4_kernel<<<256, 512, 0, stream>>>(x, a, wpack, bpack, featB);
  fc_lstm_wave<<<512, 256, 0, stream>>>((const ushort*)featB,
      (const float*)d_in[17], (const float*)d_in[18],
      (const float*)d_in[19], (const float*)d_in[20],
      (const float*)d_in[25], (const float*)d_in[26],
      (float*)d_out);
}

// Round 12
// 126.438 us; speedup vs baseline: 1.2685x; 1.0017x over previous
//
#include <hip/hip_runtime.h>
#include <hip/hip_bf16.h>

typedef __bf16   bf16x8 __attribute__((ext_vector_type(8)));
typedef float    f32x4  __attribute__((ext_vector_type(4)));
typedef _Float16 h16x2  __attribute__((ext_vector_type(2)));

#define LOG2E 1.4426950408889634f
#define LN2   0.6931471805599453f

__device__ __forceinline__ float rcp_(float x){
#if __has_builtin(__builtin_amdgcn_rcpf)
  return __builtin_amdgcn_rcpf(x);
#else
  return 1.0f / x;
#endif
}
__device__ __forceinline__ float ex2_(float x){
#if __has_builtin(__builtin_amdgcn_exp2f)
  return __builtin_amdgcn_exp2f(x);
#else
  return exp2f(x);
#endif
}
__device__ __forceinline__ float lg2_(float x){
#if __has_builtin(__builtin_amdgcn_logf)
  return __builtin_amdgcn_logf(x);
#else
  return log2f(x);
#endif
}

// pack two f32 -> f16x2 bit-pattern (int)
__device__ __forceinline__ int pkrtz_(float a, float b){
  auto v = __builtin_amdgcn_cvt_pkrtz(a, b);
  int r; __builtin_memcpy(&r, &v, 4); return r;
}
__device__ __forceinline__ h16x2 as_h2_(int x){
  h16x2 r; __builtin_memcpy(&r, &x, 4); return r;
}

#if __has_builtin(__builtin_amdgcn_fdot2)
__device__ __forceinline__ float fdot2_(int w, int h, float a){
  return __builtin_amdgcn_fdot2(as_h2_(w), as_h2_(h), a, false);
}
#else
__device__ __forceinline__ float fdot2_(int w, int h, float a){
  h16x2 wv = as_h2_(w), hv = as_h2_(h);
  return a + (float)wv[0]*(float)hv[0] + (float)wv[1]*(float)hv[1];
}
#endif

struct LstmArgs {
  const float* Wih[4]; const float* Whh[4];
  const float* bih[4]; const float* bhh[4];
  const float* h0[4];  const float* c0[4];
};

// ---------------------------------------------------------------------------
// pack_weights: fragment-lane-ordered, pre-scaled bf16x8 weight blobs +
// pre-scaled biases. wpack[((d*8+w)*4+g)*5+kk][lane] ; bpack[d*512 + grow]
// ---------------------------------------------------------------------------
__global__ void pack_weights(LstmArgs args, bf16x8* __restrict__ wpack,
                             float* __restrict__ bpack)
{
  const int idx = blockIdx.x*256 + threadIdx.x;      // 40960 total
  if (idx >= 4*8*4*5*64) return;
  const int lane = idx & 63;
  int r = idx >> 6;
  const int kk = r % 5; r /= 5;
  const int g  = r & 3; r >>= 2;
  const int w  = r & 7;
  const int d  = r >> 3;
  const int lc = lane & 15, lr4 = lane >> 4;
  const int grow = g*128 + w*16 + lc;
  const float sc = (g == 2) ? 2.0f*LOG2E : -LOG2E;

  bf16x8 v;
  if (kk < 4){
    const float* p = args.Whh[d] + grow*128 + kk*32 + lr4*8;
#pragma unroll
    for (int j = 0; j < 8; ++j) v[j] = (__bf16)(p[j] * sc);
  } else {
#pragma unroll
    for (int j = 0; j < 8; ++j){
      const int xi = lr4*8 + j;
      v[j] = (xi < 28) ? (__bf16)(args.Wih[d][grow*28 + xi] * sc) : (__bf16)0.0f;
    }
  }
  wpack[idx] = v;
  if (kk == 0 && lr4 == 0)
    bpack[d*512 + grow] = (args.bih[d][grow] + args.bhh[d][grow]) * sc;
}

// ---------------------------------------------------------------------------
// Kernel A: 4 dirs x 64 batch-blocks of 32 rows, 8 waves (512 thr), 256
// blocks = 1/CU. Weights via coalesced wpack loads (regs). x staged once.
// Double-buffered hcat -> ONE barrier per step.
// Trans-minimized activations (5 ex2 + 2 rcp per cell):
//   cc = [c*P + (Eg-1)*wf] * rcp(P*wf),  P=(1+Ei)(1+Eg), wf=1+Ef
//   hv = (Ec-1) * rcp((1+Eo)(1+Ec))
// bias enters as the C operand of the kk=0 MFMA (no per-step acc-init movs).
// ---------------------------------------------------------------------------
__global__ __launch_bounds__(512, 2) void lstm4_kernel(const float* __restrict__ x,
                                                       LstmArgs args,
                                                       const bf16x8* __restrict__ wpack,
                                                       const float* __restrict__ bpack,
                                                       __bf16* __restrict__ featB)
{
  const int dir = blockIdx.x >> 6;          // 0=lr_f 1=lr_b 2=ud_f 3=ud_b
  const int b0  = (blockIdx.x & 63) * 32;
  const int tid = threadIdx.x;
  const int w   = tid >> 6;                 // wave 0..7
  const int l   = tid & 63;
  const int lc  = l & 15;
  const int lr4 = l >> 4;

  const float* __restrict__ h0 = args.h0[dir];
  const float* __restrict__ c0 = args.c0[dir];
  const int rev = dir & 1;
  const bool lrdir = (dir < 2);

  __shared__ __align__(16) __bf16 hcat[2][32 * 168];     // 21 KiB
  __shared__ __align__(16) __bf16 xstage[28 * 32 * 40];  // 70 KiB

  // ---- B fragments: coalesced 16B loads from wpack ------------------------
  bf16x8 bfr[4][5];
  f32x4  bias_acc[4];
  {
    const bf16x8* wp = wpack + (dir*8 + w)*4*5*64;
#pragma unroll
    for (int g = 0; g < 4; ++g){
#pragma unroll
      for (int kk = 0; kk < 5; ++kk)
        bfr[g][kk] = wp[(g*5 + kk)*64 + l];
      const float b = bpack[dir*512 + g*128 + w*16 + lc];
      f32x4 bv = {b, b, b, b};
      bias_acc[g] = bv;
    }
  }

  // ---- stage x tile once, float4 global loads ------------------------------
  for (int idx = tid; idx < 32*196; idx += 512){   // 196 = 28*7 float4 per row
    const int row = idx / 196;
    const int rem = idx - row*196;
    if (lrdir){
      const int t = rem / 7, jg = rem - 7*t;
      const float4 v = *(const float4*)&x[(b0+row)*784 + t*28 + jg*4];
      __bf16* dst = &xstage[(t*32 + row)*40 + jg*4];
      dst[0]=(__bf16)v.x; dst[1]=(__bf16)v.y; dst[2]=(__bf16)v.z; dst[3]=(__bf16)v.w;
    } else {
      const int j = rem / 7, tg = rem - 7*j;
      const float4 v = *(const float4*)&x[(b0+row)*784 + j*28 + tg*4];
      xstage[((tg*4+0)*32 + row)*40 + j] = (__bf16)v.x;
      xstage[((tg*4+1)*32 + row)*40 + j] = (__bf16)v.y;
      xstage[((tg*4+2)*32 + row)*40 + j] = (__bf16)v.z;
      xstage[((tg*4+3)*32 + row)*40 + j] = (__bf16)v.w;
    }
  }
  for (int idx = tid; idx < 28*32; idx += 512){    // zero K-pad cols 28..31
    const int t = idx >> 5, row = idx & 31;
    __bf16* p = &xstage[(t*32 + row)*40 + 28];
    p[0] = p[1] = p[2] = p[3] = (__bf16)0.0f;
  }

  // ---- initial state -------------------------------------------------------
  float cst[2][4];
#pragma unroll
  for (int m = 0; m < 2; ++m)
#pragma unroll
  for (int r = 0; r < 4; ++r){
    const int row = 16*m + 4*lr4 + r;
    const int col = w*16 + lc;
    cst[m][r] = c0[(b0+row)*128 + col];
    hcat[0][row*168 + col] = (__bf16)h0[(b0+row)*128 + col];
  }
  __syncthreads();

  // ---- 28 sequential steps, ONE barrier each -------------------------------
  int cur = 0;
  for (int s = 0; s < 28; ++s){
    const int t = rev ? (27 - s) : s;
    const int nxt = cur ^ 1;

    f32x4 acc[2][4];
#pragma unroll
    for (int m = 0; m < 2; ++m){
#pragma unroll
      for (int kk = 0; kk < 5; ++kk){
        const bf16x8 a = (kk < 4)
          ? *(const bf16x8*)&hcat[cur][(16*m + lc)*168 + kk*32 + lr4*8]
          : *(const bf16x8*)&xstage[(t*32 + 16*m + lc)*40 + lr4*8];
        if (kk == 0){
#pragma unroll
          for (int g = 0; g < 4; ++g)
            acc[m][g] = __builtin_amdgcn_mfma_f32_16x16x32_bf16(a, bfr[g][0], bias_acc[g], 0, 0, 0);
        } else {
#pragma unroll
          for (int g = 0; g < 4; ++g)
            acc[m][g] = __builtin_amdgcn_mfma_f32_16x16x32_bf16(a, bfr[g][kk], acc[m][g], 0, 0, 0);
        }
      }
    }

    // trans-minimized activations: 5 ex2 + 2 rcp per cell
#pragma unroll
    for (int m = 0; m < 2; ++m)
#pragma unroll
    for (int r = 0; r < 4; ++r){
      const float Ei = ex2_(acc[m][0][r]);   // e^{-i}
      const float Ef = ex2_(acc[m][1][r]);   // e^{-f}
      const float Eg = ex2_(acc[m][2][r]);   // e^{2g}
      const float Eo = ex2_(acc[m][3][r]);   // e^{-o}
      const float u  = 1.0f + Ei;
      const float v  = 1.0f + Eg;
      const float wf = 1.0f + Ef;
      const float P  = u * v;
      const float R  = rcp_(P * wf);
      const float num = __builtin_fmaf(cst[m][r], P, (v - 2.0f) * wf);
      const float cc  = num * R;
      cst[m][r] = cc;
      const float Ec  = ex2_(2.0f*LOG2E*cc); // e^{2c}
      const float roc = rcp_((1.0f + Eo)*(1.0f + Ec));
      const float hv  = (Ec - 1.0f)*roc;     // sig(o)*tanh(c)
      hcat[nxt][(16*m + 4*lr4 + r)*168 + w*16 + lc] = (__bf16)hv;
    }
    __syncthreads();
    cur = nxt;
  }

  // ---- epilogue: final h (in hcat[cur]) -> featB[batch][512], coalesced ----
  {
    const int row = tid >> 4;      // 0..31
    const int cg  = tid & 15;      // 0..15
    const bf16x8 hv = *(const bf16x8*)&hcat[cur][row*168 + cg*8];
    *(bf16x8*)&featB[(b0+row)*512 + dir*128 + cg*8] = hv;
  }
}

// ---------------------------------------------------------------------------
// Kernel B: fc LSTM, one wave per batch element (2048 waves, 2/SIMD).
// Lanes = gate-rows 4u+g (40 active). xt from scalar s_load windows;
// h-dot via 5 fdot2 on f16 pairs packed in VALU domain (dpp + pkrtz);
// gather only sf/tg/so via quad_perm dpp. (unchanged from R11)
// ---------------------------------------------------------------------------
__global__ __launch_bounds__(256) void fc_lstm_wave(const ushort* __restrict__ featB,
                                                    const float* __restrict__ Wih,
                                                    const float* __restrict__ Whh,
                                                    const float* __restrict__ bih,
                                                    const float* __restrict__ bhh,
                                                    const float* __restrict__ h0,
                                                    const float* __restrict__ c0,
                                                    float* __restrict__ out)
{
  const int tid = threadIdx.x;
  const int l   = tid & 63;
  const int e   = blockIdx.x*4 + (tid >> 6);
  const int u   = l >> 2;                    // unit (valid < 10)
  const int g   = l & 3;                     // gate 0=i 1=f 2=g 3=o
  const int uc  = (u < 10) ? u : 9;
  const bool valid = (u < 10);
  const float sc = (g == 2) ? 2.0f*LOG2E : -LOG2E;
  const int row = g*10 + uc;

  // weights packed f16 pairs: wh2[m] = (W[row][2m], W[row][2m+1]) * sc
  int wh2[5];
#pragma unroll
  for (int m = 0; m < 5; ++m){
    const float w0 = valid ? Whh[row*10 + 2*m]   * sc : 0.0f;
    const float w1 = valid ? Whh[row*10 + 2*m+1] * sc : 0.0f;
    wh2[m] = pkrtz_(w0, w1);
  }
  const float wx   = valid ? Wih[row]*sc : 0.0f;
  const float bia  = valid ? (bih[row] + bhh[row])*sc : 0.0f;
  const float actA = (g == 2) ? 1.0f : 0.0f;
  const float actB = (g == 2) ? -2.0f : 1.0f;

  float c     = valid ? c0[e*10 + uc] : 0.0f;
  float hlast = valid ? h0[e*10 + uc] : 0.0f;

  // h-pair pack: lane 4u gets h[u+1] via DPP row_shl:4 (0x104); pairs read
  // from lanes 0,8,16,24,32 -> (h0,h1),(h2,h3),(h4,h5),(h6,h7),(h8,h9).
  int hp0, hp1, hp2, hp3, hp4;
  {
    const int hn = __builtin_amdgcn_mov_dpp(__float_as_int(hlast), 0x104, 0xF, 0xF, false);
    const int hpi = pkrtz_(hlast, __int_as_float(hn));
    hp0 = __builtin_amdgcn_readlane(hpi,  0);
    hp1 = __builtin_amdgcn_readlane(hpi,  8);
    hp2 = __builtin_amdgcn_readlane(hpi, 16);
    hp3 = __builtin_amdgcn_readlane(hpi, 24);
    hp4 = __builtin_amdgcn_readlane(hpi, 32);
  }

  // ---- scalarized featB pointer (wave-uniform) -> s_load windows -----------
  const uint4* fBs;
  {
    unsigned long long a = (unsigned long long)(uintptr_t)(featB + (size_t)e*512);
    unsigned lo = (unsigned)__builtin_amdgcn_readfirstlane((int)(a & 0xffffffffu));
    unsigned hi = (unsigned)__builtin_amdgcn_readfirstlane((int)(a >> 32));
    fBs = (const uint4*)(uintptr_t)(((unsigned long long)hi << 32) | lo);
  }

  unsigned int cur[8][4], nxt[8][4];   // two 64-step windows (bf16 pairs)
#pragma unroll
  for (int k = 0; k < 8; ++k){
    const uint4 q0 = fBs[k];
    cur[k][0]=q0.x; cur[k][1]=q0.y; cur[k][2]=q0.z; cur[k][3]=q0.w;
    const uint4 q1 = fBs[8 + k];
    nxt[k][0]=q1.x; nxt[k][1]=q1.y; nxt[k][2]=q1.z; nxt[k][3]=q1.w;
  }

  for (int win = 0; win < 8; ++win){
#pragma unroll
    for (int blk = 0; blk < 8; ++blk){
#pragma unroll
      for (int jj = 0; jj < 8; ++jj){
        const unsigned d  = cur[blk][jj >> 1];
        const unsigned xb = (jj & 1) ? (d & 0xffff0000u) : (d << 16);
        const float xs = __int_as_float((int)xb);
        // dot: 1 fma + 5 fdot2 (2 accumulators) + 1 add
        float a0 = __builtin_fmaf(wx, xs, bia);
        a0 = fdot2_(wh2[0], hp0, a0);
        float a1 = fdot2_(wh2[1], hp1, 0.0f);
        a0 = fdot2_(wh2[2], hp2, a0);
        a1 = fdot2_(wh2[3], hp3, a1);
        a0 = fdot2_(wh2[4], hp4, a0);
        const float acc = a0 + a1;
        const float rc  = rcp_(1.0f + ex2_(acc));
        const float val = __builtin_fmaf(actB, rc, actA);
        const int   vi  = __float_as_int(val);
        // gather only sf/tg/so (c,h valid on g==0 lanes only; val there = si)
        const float tg  = __int_as_float(__builtin_amdgcn_mov_dpp(vi, 0xAA, 0xF, 0xF, false));
        const float sf  = __int_as_float(__builtin_amdgcn_mov_dpp(vi, 0x55, 0xF, 0xF, false));
        const float so  = __int_as_float(__builtin_amdgcn_mov_dpp(vi, 0xFF, 0xF, 0xF, false));
        c = __builtin_fmaf(sf, c, val*tg);
        const float tc = __builtin_fmaf(-2.0f, rcp_(1.0f + ex2_(2.0f*LOG2E*c)), 1.0f);
        const float h  = so*tc;
        hlast = h;
        const int hn  = __builtin_amdgcn_mov_dpp(__float_as_int(h), 0x104, 0xF, 0xF, false);
        const int hpi = pkrtz_(h, __int_as_float(hn));
        hp0 = __builtin_amdgcn_readlane(hpi,  0);
        hp1 = __builtin_amdgcn_readlane(hpi,  8);
        hp2 = __builtin_amdgcn_readlane(hpi, 16);
        hp3 = __builtin_amdgcn_readlane(hpi, 24);
        hp4 = __builtin_amdgcn_readlane(hpi, 32);
      }
    }
#pragma unroll
    for (int k = 0; k < 8; ++k){
      cur[k][0]=nxt[k][0]; cur[k][1]=nxt[k][1];
      cur[k][2]=nxt[k][2]; cur[k][3]=nxt[k][3];
    }
    if (win < 6){
#pragma unroll
      for (int k = 0; k < 8; ++k){
        const uint4 q = fBs[(win + 2)*8 + k];
        nxt[k][0]=q.x; nxt[k][1]=q.y; nxt[k][2]=q.z; nxt[k][3]=q.w;
      }
    }
  }

  // ---- log-softmax over units 0..9 (h valid on g==0 lanes) ------------------
  const int hb = __float_as_int(hlast);
  float sh[10];
#pragma unroll
  for (int m = 0; m < 10; ++m)
    sh[m] = __int_as_float(__builtin_amdgcn_readlane(hb, 4*m));
  float mx = sh[0];
#pragma unroll
  for (int m = 1; m < 10; ++m) mx = fmaxf(mx, sh[m]);
  float es = 0.0f;
#pragma unroll
  for (int m = 0; m < 10; ++m) es += ex2_(LOG2E*(sh[m] - mx));
  const float lse = LN2 * lg2_(es);
  if (valid && g == 0) out[e*10 + u] = hlast - mx - lse;
}

extern "C" void kernel_launch(void* const* d_in, const int* in_sizes, int n_in,
                              void* d_out, int out_size, void* d_ws, size_t ws_size,
                              hipStream_t stream)
{
  const float* x = (const float*)d_in[0];
  LstmArgs a;
  const int base[4] = {1, 5, 9, 13};   // lr_f, lr_b, ud_f, ud_b
  for (int d = 0; d < 4; ++d){
    a.Wih[d] = (const float*)d_in[base[d] + 0];
    a.Whh[d] = (const float*)d_in[base[d] + 1];
    a.bih[d] = (const float*)d_in[base[d] + 2];
    a.bhh[d] = (const float*)d_in[base[d] + 3];
  }
  const float* h0lr = (const float*)d_in[21];
  const float* c0lr = (const float*)d_in[22];
  const float* h0ud = (const float*)d_in[23];
  const float* c0ud = (const float*)d_in[24];
  a.h0[0] = h0lr;               a.c0[0] = c0lr;
  a.h0[1] = h0lr + 2048*128;    a.c0[1] = c0lr + 2048*128;
  a.h0[2] = h0ud;               a.c0[2] = c0ud;
  a.h0[3] = h0ud + 2048*128;    a.c0[3] = c0ud + 2048*128;

  char* ws = (char*)d_ws;
  __bf16* featB = (__bf16*)ws;                          // 2048*512*2 = 2 MiB
  bf16x8* wpack = (bf16x8*)(ws + (2u<<20));             // 40960*16 = 640 KiB
  float*  bpack = (float*)(ws + (2u<<20) + 655360u);    // 2048*4 = 8 KiB

  pack_weights<<<160, 256, 0, stream>>>(a, wpack, bpack);
  lstm4_kernel<<<256, 512, 0, stream>>>(x, a, wpack, bpack, featB);
  fc_lstm_wave<<<512, 256, 0, stream>>>((const ushort*)featB,
      (const float*)d_in[17], (const float*)d_in[18],
      (const float*)d_in[19], (const float*)d_in[20],
      (const float*)d_in[25], (const float*)d_in[26],
      (float*)d_out);
}

// Round 13
// 122.265 us; speedup vs baseline: 1.3119x; 1.0341x over previous
//
#include <hip/hip_runtime.h>
#include <hip/hip_bf16.h>

typedef __bf16   bf16x8 __attribute__((ext_vector_type(8)));
typedef float    f32x4  __attribute__((ext_vector_type(4)));
typedef _Float16 h16x2  __attribute__((ext_vector_type(2)));

#define LOG2E 1.4426950408889634f
#define LN2   0.6931471805599453f

__device__ __forceinline__ float rcp_(float x){
#if __has_builtin(__builtin_amdgcn_rcpf)
  return __builtin_amdgcn_rcpf(x);
#else
  return 1.0f / x;
#endif
}
__device__ __forceinline__ float ex2_(float x){
#if __has_builtin(__builtin_amdgcn_exp2f)
  return __builtin_amdgcn_exp2f(x);
#else
  return exp2f(x);
#endif
}
__device__ __forceinline__ float lg2_(float x){
#if __has_builtin(__builtin_amdgcn_logf)
  return __builtin_amdgcn_logf(x);
#else
  return log2f(x);
#endif
}

// pack two f32 -> f16x2 bit-pattern (int)
__device__ __forceinline__ int pkrtz_(float a, float b){
  auto v = __builtin_amdgcn_cvt_pkrtz(a, b);
  int r; __builtin_memcpy(&r, &v, 4); return r;
}
__device__ __forceinline__ h16x2 as_h2_(int x){
  h16x2 r; __builtin_memcpy(&r, &x, 4); return r;
}

#if __has_builtin(__builtin_amdgcn_fdot2)
__device__ __forceinline__ float fdot2_(int w, int h, float a){
  return __builtin_amdgcn_fdot2(as_h2_(w), as_h2_(h), a, false);
}
#else
__device__ __forceinline__ float fdot2_(int w, int h, float a){
  h16x2 wv = as_h2_(w), hv = as_h2_(h);
  return a + (float)wv[0]*(float)hv[0] + (float)wv[1]*(float)hv[1];
}
#endif

struct LstmArgs {
  const float* Wih[4]; const float* Whh[4];
  const float* bih[4]; const float* bhh[4];
  const float* h0[4];  const float* c0[4];
};

// ---------------------------------------------------------------------------
// pack_weights: fragment-lane-ordered, pre-scaled bf16x8 weight blobs.
// wpack[((d*8+w)*4+g)*5+kk][lane]. BIAS IS FOLDED INTO THE x-PART (kk=4)
// at K-column 28 (xstage column 28 is constant 1.0): no bias regs in lstm4.
// ---------------------------------------------------------------------------
__global__ void pack_weights(LstmArgs args, bf16x8* __restrict__ wpack)
{
  const int idx = blockIdx.x*256 + threadIdx.x;      // 40960 total
  if (idx >= 4*8*4*5*64) return;
  const int lane = idx & 63;
  int r = idx >> 6;
  const int kk = r % 5; r /= 5;
  const int g  = r & 3; r >>= 2;
  const int w  = r & 7;
  const int d  = r >> 3;
  const int lc = lane & 15, lr4 = lane >> 4;
  const int grow = g*128 + w*16 + lc;
  const float sc = (g == 2) ? 2.0f*LOG2E : -LOG2E;

  bf16x8 v;
  if (kk < 4){
    const float* p = args.Whh[d] + grow*128 + kk*32 + lr4*8;
#pragma unroll
    for (int j = 0; j < 8; ++j) v[j] = (__bf16)(p[j] * sc);
  } else {
#pragma unroll
    for (int j = 0; j < 8; ++j){
      const int xi = lr4*8 + j;
      float wv;
      if (xi < 28)       wv = args.Wih[d][grow*28 + xi] * sc;
      else if (xi == 28) wv = (args.bih[d][grow] + args.bhh[d][grow]) * sc;
      else               wv = 0.0f;
      v[j] = (__bf16)wv;
    }
  }
  wpack[idx] = v;
}

// ---------------------------------------------------------------------------
// Kernel A: 4 dirs x 128 batch-blocks of 16 rows, 8 waves (512 thr),
// 512 blocks -> TWO blocks/CU co-resident (LDS 45.5 KiB, VGPR<=128 via
// launch_bounds(512,4)): independent barrier groups fill each other's
// dependency stalls. Bias flows through the kk=4 MFMA (x-pad col 28 = 1.0);
// acc starts from a shared zero-quad. ONE barrier/step (dbuf hcat).
// Trans-minimized activations: 5 ex2 + 2 rcp per cell.
// ---------------------------------------------------------------------------
__global__ __launch_bounds__(512, 4) void lstm4_kernel(const float* __restrict__ x,
                                                       LstmArgs args,
                                                       const bf16x8* __restrict__ wpack,
                                                       __bf16* __restrict__ featB)
{
  const int dir = blockIdx.x >> 7;          // 0=lr_f 1=lr_b 2=ud_f 3=ud_b
  const int b0  = (blockIdx.x & 127) * 16;
  const int tid = threadIdx.x;
  const int w   = tid >> 6;                 // wave 0..7
  const int l   = tid & 63;
  const int lc  = l & 15;
  const int lr4 = l >> 4;

  const float* __restrict__ h0 = args.h0[dir];
  const float* __restrict__ c0 = args.c0[dir];
  const int rev = dir & 1;
  const bool lrdir = (dir < 2);

  __shared__ __align__(16) __bf16 hcat[2][16 * 168];     // 10.5 KiB
  __shared__ __align__(16) __bf16 xstage[28 * 16 * 40];  // 35 KiB

  // ---- B fragments: coalesced 16B loads from wpack ------------------------
  bf16x8 bfr[4][5];
  {
    const bf16x8* wp = wpack + (dir*8 + w)*4*5*64;
#pragma unroll
    for (int g = 0; g < 4; ++g)
#pragma unroll
      for (int kk = 0; kk < 5; ++kk)
        bfr[g][kk] = wp[(g*5 + kk)*64 + l];
  }

  // ---- stage x tile once, float4 global loads ------------------------------
  for (int idx = tid; idx < 16*196; idx += 512){   // 196 = 28*7 float4 per row
    const int row = idx / 196;
    const int rem = idx - row*196;
    if (lrdir){
      const int t = rem / 7, jg = rem - 7*t;
      const float4 v = *(const float4*)&x[(b0+row)*784 + t*28 + jg*4];
      __bf16* dst = &xstage[(t*16 + row)*40 + jg*4];
      dst[0]=(__bf16)v.x; dst[1]=(__bf16)v.y; dst[2]=(__bf16)v.z; dst[3]=(__bf16)v.w;
    } else {
      const int j = rem / 7, tg = rem - 7*j;
      const float4 v = *(const float4*)&x[(b0+row)*784 + j*28 + tg*4];
      xstage[((tg*4+0)*16 + row)*40 + j] = (__bf16)v.x;
      xstage[((tg*4+1)*16 + row)*40 + j] = (__bf16)v.y;
      xstage[((tg*4+2)*16 + row)*40 + j] = (__bf16)v.z;
      xstage[((tg*4+3)*16 + row)*40 + j] = (__bf16)v.w;
    }
  }
  if (tid < 28*16){                  // pad: col 28 = 1.0 (bias), 29..31 = 0
    const int t = tid >> 4, row = tid & 15;
    __bf16* p = &xstage[(t*16 + row)*40 + 28];
    p[0] = (__bf16)1.0f; p[1] = (__bf16)0.0f; p[2] = (__bf16)0.0f; p[3] = (__bf16)0.0f;
  }

  // ---- initial state -------------------------------------------------------
  float cst[4];
#pragma unroll
  for (int r = 0; r < 4; ++r){
    const int row = 4*lr4 + r;
    const int col = w*16 + lc;
    cst[r] = c0[(b0+row)*128 + col];
    hcat[0][row*168 + col] = (__bf16)h0[(b0+row)*128 + col];
  }
  __syncthreads();

  const f32x4 zacc = {0.0f, 0.0f, 0.0f, 0.0f};

  // ---- 28 sequential steps, ONE barrier each -------------------------------
  int cur = 0;
  for (int s = 0; s < 28; ++s){
    const int t = rev ? (27 - s) : s;
    const int nxt = cur ^ 1;

    f32x4 acc[4];
#pragma unroll
    for (int kk = 0; kk < 5; ++kk){
      const bf16x8 a = (kk < 4)
        ? *(const bf16x8*)&hcat[cur][lc*168 + kk*32 + lr4*8]
        : *(const bf16x8*)&xstage[(t*16 + lc)*40 + lr4*8];
      if (kk == 0){
#pragma unroll
        for (int g = 0; g < 4; ++g)
          acc[g] = __builtin_amdgcn_mfma_f32_16x16x32_bf16(a, bfr[g][0], zacc, 0, 0, 0);
      } else {
#pragma unroll
        for (int g = 0; g < 4; ++g)
          acc[g] = __builtin_amdgcn_mfma_f32_16x16x32_bf16(a, bfr[g][kk], acc[g], 0, 0, 0);
      }
    }

    // trans-minimized activations: 5 ex2 + 2 rcp per cell
#pragma unroll
    for (int r = 0; r < 4; ++r){
      const float Ei = ex2_(acc[0][r]);   // e^{-i}
      const float Ef = ex2_(acc[1][r]);   // e^{-f}
      const float Eg = ex2_(acc[2][r]);   // e^{2g}
      const float Eo = ex2_(acc[3][r]);   // e^{-o}
      const float u  = 1.0f + Ei;
      const float v  = 1.0f + Eg;
      const float wf = 1.0f + Ef;
      const float P  = u * v;
      const float R  = rcp_(P * wf);
      const float num = __builtin_fmaf(cst[r], P, (v - 2.0f) * wf);
      const float cc  = num * R;
      cst[r] = cc;
      const float Ec  = ex2_(2.0f*LOG2E*cc); // e^{2c}
      const float roc = rcp_((1.0f + Eo)*(1.0f + Ec));
      const float hv  = (Ec - 1.0f)*roc;     // sig(o)*tanh(c)
      hcat[nxt][(4*lr4 + r)*168 + w*16 + lc] = (__bf16)hv;
    }
    __syncthreads();
    cur = nxt;
  }

  // ---- epilogue: final h (in hcat[cur]) -> featB[batch][512], coalesced ----
  if (tid < 256){
    const int row = tid >> 4;      // 0..15
    const int cg  = tid & 15;      // 0..15
    const bf16x8 hv = *(const bf16x8*)&hcat[cur][row*168 + cg*8];
    *(bf16x8*)&featB[(b0+row)*512 + dir*128 + cg*8] = hv;
  }
}

// ---------------------------------------------------------------------------
// Kernel B: fc LSTM, one wave per batch element (2048 waves, 2/SIMD).
// Lanes = gate-rows 4u+g (40 active). xt from scalar s_load windows;
// h-dot via 5 fdot2 on f16 pairs packed in VALU domain (dpp + pkrtz);
// gather only sf/tg/so via quad_perm dpp. (unchanged from R12)
// ---------------------------------------------------------------------------
__global__ __launch_bounds__(256) void fc_lstm_wave(const ushort* __restrict__ featB,
                                                    const float* __restrict__ Wih,
                                                    const float* __restrict__ Whh,
                                                    const float* __restrict__ bih,
                                                    const float* __restrict__ bhh,
                                                    const float* __restrict__ h0,
                                                    const float* __restrict__ c0,
                                                    float* __restrict__ out)
{
  const int tid = threadIdx.x;
  const int l   = tid & 63;
  const int e   = blockIdx.x*4 + (tid >> 6);
  const int u   = l >> 2;                    // unit (valid < 10)
  const int g   = l & 3;                     // gate 0=i 1=f 2=g 3=o
  const int uc  = (u < 10) ? u : 9;
  const bool valid = (u < 10);
  const float sc = (g == 2) ? 2.0f*LOG2E : -LOG2E;
  const int row = g*10 + uc;

  // weights packed f16 pairs: wh2[m] = (W[row][2m], W[row][2m+1]) * sc
  int wh2[5];
#pragma unroll
  for (int m = 0; m < 5; ++m){
    const float w0 = valid ? Whh[row*10 + 2*m]   * sc : 0.0f;
    const float w1 = valid ? Whh[row*10 + 2*m+1] * sc : 0.0f;
    wh2[m] = pkrtz_(w0, w1);
  }
  const float wx   = valid ? Wih[row]*sc : 0.0f;
  const float bia  = valid ? (bih[row] + bhh[row])*sc : 0.0f;
  const float actA = (g == 2) ? 1.0f : 0.0f;
  const float actB = (g == 2) ? -2.0f : 1.0f;

  float c     = valid ? c0[e*10 + uc] : 0.0f;
  float hlast = valid ? h0[e*10 + uc] : 0.0f;

  // h-pair pack: lane 4u gets h[u+1] via DPP row_shl:4 (0x104); pairs read
  // from lanes 0,8,16,24,32 -> (h0,h1),(h2,h3),(h4,h5),(h6,h7),(h8,h9).
  int hp0, hp1, hp2, hp3, hp4;
  {
    const int hn = __builtin_amdgcn_mov_dpp(__float_as_int(hlast), 0x104, 0xF, 0xF, false);
    const int hpi = pkrtz_(hlast, __int_as_float(hn));
    hp0 = __builtin_amdgcn_readlane(hpi,  0);
    hp1 = __builtin_amdgcn_readlane(hpi,  8);
    hp2 = __builtin_amdgcn_readlane(hpi, 16);
    hp3 = __builtin_amdgcn_readlane(hpi, 24);
    hp4 = __builtin_amdgcn_readlane(hpi, 32);
  }

  // ---- scalarized featB pointer (wave-uniform) -> s_load windows -----------
  const uint4* fBs;
  {
    unsigned long long a = (unsigned long long)(uintptr_t)(featB + (size_t)e*512);
    unsigned lo = (unsigned)__builtin_amdgcn_readfirstlane((int)(a & 0xffffffffu));
    unsigned hi = (unsigned)__builtin_amdgcn_readfirstlane((int)(a >> 32));
    fBs = (const uint4*)(uintptr_t)(((unsigned long long)hi << 32) | lo);
  }

  unsigned int cur[8][4], nxt[8][4];   // two 64-step windows (bf16 pairs)
#pragma unroll
  for (int k = 0; k < 8; ++k){
    const uint4 q0 = fBs[k];
    cur[k][0]=q0.x; cur[k][1]=q0.y; cur[k][2]=q0.z; cur[k][3]=q0.w;
    const uint4 q1 = fBs[8 + k];
    nxt[k][0]=q1.x; nxt[k][1]=q1.y; nxt[k][2]=q1.z; nxt[k][3]=q1.w;
  }

  for (int win = 0; win < 8; ++win){
#pragma unroll
    for (int blk = 0; blk < 8; ++blk){
#pragma unroll
      for (int jj = 0; jj < 8; ++jj){
        const unsigned d  = cur[blk][jj >> 1];
        const unsigned xb = (jj & 1) ? (d & 0xffff0000u) : (d << 16);
        const float xs = __int_as_float((int)xb);
        // dot: 1 fma + 5 fdot2 (2 accumulators) + 1 add
        float a0 = __builtin_fmaf(wx, xs, bia);
        a0 = fdot2_(wh2[0], hp0, a0);
        float a1 = fdot2_(wh2[1], hp1, 0.0f);
        a0 = fdot2_(wh2[2], hp2, a0);
        a1 = fdot2_(wh2[3], hp3, a1);
        a0 = fdot2_(wh2[4], hp4, a0);
        const float acc = a0 + a1;
        const float rc  = rcp_(1.0f + ex2_(acc));
        const float val = __builtin_fmaf(actB, rc, actA);
        const int   vi  = __float_as_int(val);
        // gather only sf/tg/so (c,h valid on g==0 lanes only; val there = si)
        const float tg  = __int_as_float(__builtin_amdgcn_mov_dpp(vi, 0xAA, 0xF, 0xF, false));
        const float sf  = __int_as_float(__builtin_amdgcn_mov_dpp(vi, 0x55, 0xF, 0xF, false));
        const float so  = __int_as_float(__builtin_amdgcn_mov_dpp(vi, 0xFF, 0xF, 0xF, false));
        c = __builtin_fmaf(sf, c, val*tg);
        const float tc = __builtin_fmaf(-2.0f, rcp_(1.0f + ex2_(2.0f*LOG2E*c)), 1.0f);
        const float h  = so*tc;
        hlast = h;
        const int hn  = __builtin_amdgcn_mov_dpp(__float_as_int(h), 0x104, 0xF, 0xF, false);
        const int hpi = pkrtz_(h, __int_as_float(hn));
        hp0 = __builtin_amdgcn_readlane(hpi,  0);
        hp1 = __builtin_amdgcn_readlane(hpi,  8);
        hp2 = __builtin_amdgcn_readlane(hpi, 16);
        hp3 = __builtin_amdgcn_readlane(hpi, 24);
        hp4 = __builtin_amdgcn_readlane(hpi, 32);
      }
    }
#pragma unroll
    for (int k = 0; k < 8; ++k){
      cur[k][0]=nxt[k][0]; cur[k][1]=nxt[k][1];
      cur[k][2]=nxt[k][2]; cur[k][3]=nxt[k][3];
    }
    if (win < 6){
#pragma unroll
      for (int k = 0; k < 8; ++k){
        const uint4 q = fBs[(win + 2)*8 + k];
        nxt[k][0]=q.x; nxt[k][1]=q.y; nxt[k][2]=q.z; nxt[k][3]=q.w;
      }
    }
  }

  // ---- log-softmax over units 0..9 (h valid on g==0 lanes) ------------------
  const int hb = __float_as_int(hlast);
  float sh[10];
#pragma unroll
  for (int m = 0; m < 10; ++m)
    sh[m] = __int_as_float(__builtin_amdgcn_readlane(hb, 4*m));
  float mx = sh[0];
#pragma unroll
  for (int m = 1; m < 10; ++m) mx = fmaxf(mx, sh[m]);
  float es = 0.0f;
#pragma unroll
  for (int m = 0; m < 10; ++m) es += ex2_(LOG2E*(sh[m] - mx));
  const float lse = LN2 * lg2_(es);
  if (valid && g == 0) out[e*10 + u] = hlast - mx - lse;
}

extern "C" void kernel_launch(void* const* d_in, const int* in_sizes, int n_in,
                              void* d_out, int out_size, void* d_ws, size_t ws_size,
                              hipStream_t stream)
{
  const float* x = (const float*)d_in[0];
  LstmArgs a;
  const int base[4] = {1, 5, 9, 13};   // lr_f, lr_b, ud_f, ud_b
  for (int d = 0; d < 4; ++d){
    a.Wih[d] = (const float*)d_in[base[d] + 0];
    a.Whh[d] = (const float*)d_in[base[d] + 1];
    a.bih[d] = (const float*)d_in[base[d] + 2];
    a.bhh[d] = (const float*)d_in[base[d] + 3];
  }
  const float* h0lr = (const float*)d_in[21];
  const float* c0lr = (const float*)d_in[22];
  const float* h0ud = (const float*)d_in[23];
  const float* c0ud = (const float*)d_in[24];
  a.h0[0] = h0lr;               a.c0[0] = c0lr;
  a.h0[1] = h0lr + 2048*128;    a.c0[1] = c0lr + 2048*128;
  a.h0[2] = h0ud;               a.c0[2] = c0ud;
  a.h0[3] = h0ud + 2048*128;    a.c0[3] = c0ud + 2048*128;

  char* ws = (char*)d_ws;
  __bf16* featB = (__bf16*)ws;                          // 2048*512*2 = 2 MiB
  bf16x8* wpack = (bf16x8*)(ws + (2u<<20));             // 40960*16 = 640 KiB

  pack_weights<<<160, 256, 0, stream>>>(a, wpack);
  lstm4_kernel<<<512, 512, 0, stream>>>(x, a, wpack, featB);
  fc_lstm_wave<<<512, 256, 0, stream>>>((const ushort*)featB,
      (const float*)d_in[17], (const float*)d_in[18],
      (const float*)d_in[19], (const float*)d_in[20],
      (const float*)d_in[25], (const float*)d_in[26],
      (float*)d_out);
}

// Round 14
// 122.195 us; speedup vs baseline: 1.3126x; 1.0006x over previous
//
#include <hip/hip_runtime.h>
#include <hip/hip_bf16.h>

typedef __bf16   bf16x8 __attribute__((ext_vector_type(8)));
typedef float    f32x4  __attribute__((ext_vector_type(4)));
typedef _Float16 h16x2  __attribute__((ext_vector_type(2)));

#define LOG2E 1.4426950408889634f
#define LN2   0.6931471805599453f

__device__ __forceinline__ float rcp_(float x){
#if __has_builtin(__builtin_amdgcn_rcpf)
  return __builtin_amdgcn_rcpf(x);
#else
  return 1.0f / x;
#endif
}
__device__ __forceinline__ float ex2_(float x){
#if __has_builtin(__builtin_amdgcn_exp2f)
  return __builtin_amdgcn_exp2f(x);
#else
  return exp2f(x);
#endif
}
__device__ __forceinline__ float lg2_(float x){
#if __has_builtin(__builtin_amdgcn_logf)
  return __builtin_amdgcn_logf(x);
#else
  return log2f(x);
#endif
}

// pack two f32 -> f16x2 bit-pattern (int)
__device__ __forceinline__ int pkrtz_(float a, float b){
  auto v = __builtin_amdgcn_cvt_pkrtz(a, b);
  int r; __builtin_memcpy(&r, &v, 4); return r;
}
__device__ __forceinline__ h16x2 as_h2_(int x){
  h16x2 r; __builtin_memcpy(&r, &x, 4); return r;
}

#if __has_builtin(__builtin_amdgcn_fdot2)
__device__ __forceinline__ float fdot2_(int w, int h, float a){
  return __builtin_amdgcn_fdot2(as_h2_(w), as_h2_(h), a, false);
}
#else
__device__ __forceinline__ float fdot2_(int w, int h, float a){
  h16x2 wv = as_h2_(w), hv = as_h2_(h);
  return a + (float)wv[0]*(float)hv[0] + (float)wv[1]*(float)hv[1];
}
#endif

struct LstmArgs {
  const float* Wih[4]; const float* Whh[4];
  const float* bih[4]; const float* bhh[4];
  const float* h0[4];  const float* c0[4];
};

// ---------------------------------------------------------------------------
// pack_weights: fragment-lane-ordered, pre-scaled bf16x8 weight blobs.
// wpack[((d*8+w)*4+g)*5+kk][lane]. Bias folded into the x-part (kk=4) at
// K-column 28 (xstage column 28 is constant 1.0).
// ---------------------------------------------------------------------------
__global__ void pack_weights(LstmArgs args, bf16x8* __restrict__ wpack)
{
  const int idx = blockIdx.x*256 + threadIdx.x;      // 40960 total
  if (idx >= 4*8*4*5*64) return;
  const int lane = idx & 63;
  int r = idx >> 6;
  const int kk = r % 5; r /= 5;
  const int g  = r & 3; r >>= 2;
  const int w  = r & 7;
  const int d  = r >> 3;
  const int lc = lane & 15, lr4 = lane >> 4;
  const int grow = g*128 + w*16 + lc;
  const float sc = (g == 2) ? 2.0f*LOG2E : -LOG2E;

  bf16x8 v;
  if (kk < 4){
    const float* p = args.Whh[d] + grow*128 + kk*32 + lr4*8;
#pragma unroll
    for (int j = 0; j < 8; ++j) v[j] = (__bf16)(p[j] * sc);
  } else {
#pragma unroll
    for (int j = 0; j < 8; ++j){
      const int xi = lr4*8 + j;
      float wv;
      if (xi < 28)       wv = args.Wih[d][grow*28 + xi] * sc;
      else if (xi == 28) wv = (args.bih[d][grow] + args.bhh[d][grow]) * sc;
      else               wv = 0.0f;
      v[j] = (__bf16)wv;
    }
  }
  wpack[idx] = v;
}

// ---------------------------------------------------------------------------
// Kernel A: 4 dirs x 128 batch-blocks of 16 rows, 8 waves (512 thr),
// 512 blocks -> TWO blocks/CU (LDS 45.5 KiB, VGPR<=128). ONE barrier/step.
// A-fragment ds_reads hoisted so the 5 LDS latencies overlap; MFMA block
// wrapped in setprio(1) so the compute-phase wave wins CU arbitration
// against the co-resident block's staging waves.
// ---------------------------------------------------------------------------
__global__ __launch_bounds__(512, 4) void lstm4_kernel(const float* __restrict__ x,
                                                       LstmArgs args,
                                                       const bf16x8* __restrict__ wpack,
                                                       __bf16* __restrict__ featB)
{
  const int dir = blockIdx.x >> 7;          // 0=lr_f 1=lr_b 2=ud_f 3=ud_b
  const int b0  = (blockIdx.x & 127) * 16;
  const int tid = threadIdx.x;
  const int w   = tid >> 6;                 // wave 0..7
  const int l   = tid & 63;
  const int lc  = l & 15;
  const int lr4 = l >> 4;

  const float* __restrict__ h0 = args.h0[dir];
  const float* __restrict__ c0 = args.c0[dir];
  const int rev = dir & 1;
  const bool lrdir = (dir < 2);

  __shared__ __align__(16) __bf16 hcat[2][16 * 168];     // 10.5 KiB
  __shared__ __align__(16) __bf16 xstage[28 * 16 * 40];  // 35 KiB

  // ---- B fragments: coalesced 16B loads from wpack ------------------------
  bf16x8 bfr[4][5];
  {
    const bf16x8* wp = wpack + (dir*8 + w)*4*5*64;
#pragma unroll
    for (int g = 0; g < 4; ++g)
#pragma unroll
      for (int kk = 0; kk < 5; ++kk)
        bfr[g][kk] = wp[(g*5 + kk)*64 + l];
  }

  // ---- stage x tile once, float4 global loads ------------------------------
  for (int idx = tid; idx < 16*196; idx += 512){   // 196 = 28*7 float4 per row
    const int row = idx / 196;
    const int rem = idx - row*196;
    if (lrdir){
      const int t = rem / 7, jg = rem - 7*t;
      const float4 v = *(const float4*)&x[(b0+row)*784 + t*28 + jg*4];
      __bf16* dst = &xstage[(t*16 + row)*40 + jg*4];
      dst[0]=(__bf16)v.x; dst[1]=(__bf16)v.y; dst[2]=(__bf16)v.z; dst[3]=(__bf16)v.w;
    } else {
      const int j = rem / 7, tg = rem - 7*j;
      const float4 v = *(const float4*)&x[(b0+row)*784 + j*28 + tg*4];
      xstage[((tg*4+0)*16 + row)*40 + j] = (__bf16)v.x;
      xstage[((tg*4+1)*16 + row)*40 + j] = (__bf16)v.y;
      xstage[((tg*4+2)*16 + row)*40 + j] = (__bf16)v.z;
      xstage[((tg*4+3)*16 + row)*40 + j] = (__bf16)v.w;
    }
  }
  if (tid < 28*16){                  // pad: col 28 = 1.0 (bias), 29..31 = 0
    const int t = tid >> 4, row = tid & 15;
    __bf16* p = &xstage[(t*16 + row)*40 + 28];
    p[0] = (__bf16)1.0f; p[1] = (__bf16)0.0f; p[2] = (__bf16)0.0f; p[3] = (__bf16)0.0f;
  }

  // ---- initial state -------------------------------------------------------
  float cst[4];
#pragma unroll
  for (int r = 0; r < 4; ++r){
    const int row = 4*lr4 + r;
    const int col = w*16 + lc;
    cst[r] = c0[(b0+row)*128 + col];
    hcat[0][row*168 + col] = (__bf16)h0[(b0+row)*128 + col];
  }
  __syncthreads();

  const f32x4 zacc = {0.0f, 0.0f, 0.0f, 0.0f};

  // ---- 28 sequential steps, ONE barrier each -------------------------------
  int cur = 0;
  for (int s = 0; s < 28; ++s){
    const int t = rev ? (27 - s) : s;
    const int nxt = cur ^ 1;

    // hoisted A-fragment loads: all 5 ds_read_b128 issue back-to-back
    bf16x8 afr[5];
#pragma unroll
    for (int kk = 0; kk < 4; ++kk)
      afr[kk] = *(const bf16x8*)&hcat[cur][lc*168 + kk*32 + lr4*8];
    afr[4] = *(const bf16x8*)&xstage[(t*16 + lc)*40 + lr4*8];

    __builtin_amdgcn_s_setprio(1);
    f32x4 acc[4];
#pragma unroll
    for (int g = 0; g < 4; ++g)
      acc[g] = __builtin_amdgcn_mfma_f32_16x16x32_bf16(afr[0], bfr[g][0], zacc, 0, 0, 0);
#pragma unroll
    for (int kk = 1; kk < 5; ++kk)
#pragma unroll
      for (int g = 0; g < 4; ++g)
        acc[g] = __builtin_amdgcn_mfma_f32_16x16x32_bf16(afr[kk], bfr[g][kk], acc[g], 0, 0, 0);

    // trans-minimized activations: 5 ex2 + 2 rcp per cell
#pragma unroll
    for (int r = 0; r < 4; ++r){
      const float Ei = ex2_(acc[0][r]);   // e^{-i}
      const float Ef = ex2_(acc[1][r]);   // e^{-f}
      const float Eg = ex2_(acc[2][r]);   // e^{2g}
      const float Eo = ex2_(acc[3][r]);   // e^{-o}
      const float u  = 1.0f + Ei;
      const float v  = 1.0f + Eg;
      const float wf = 1.0f + Ef;
      const float P  = u * v;
      const float R  = rcp_(P * wf);
      const float num = __builtin_fmaf(cst[r], P, (v - 2.0f) * wf);
      const float cc  = num * R;
      cst[r] = cc;
      const float Ec  = ex2_(2.0f*LOG2E*cc); // e^{2c}
      const float roc = rcp_((1.0f + Eo)*(1.0f + Ec));
      const float hv  = (Ec - 1.0f)*roc;     // sig(o)*tanh(c)
      hcat[nxt][(4*lr4 + r)*168 + w*16 + lc] = (__bf16)hv;
    }
    __builtin_amdgcn_s_setprio(0);
    __syncthreads();
    cur = nxt;
  }

  // ---- epilogue: final h (in hcat[cur]) -> featB[batch][512], coalesced ----
  if (tid < 256){
    const int row = tid >> 4;      // 0..15
    const int cg  = tid & 15;      // 0..15
    const bf16x8 hv = *(const bf16x8*)&hcat[cur][row*168 + cg*8];
    *(bf16x8*)&featB[(b0+row)*512 + dir*128 + cg*8] = hv;
  }
}

// ---------------------------------------------------------------------------
// Kernel B: fc LSTM, one wave per batch element (2048 waves, 2/SIMD).
// Lanes = gate-rows 4u+g (40 active). xt from scalar s_load windows;
// h-dot via 5 fdot2 on f16 pairs packed in VALU domain (dpp + pkrtz);
// gather only sf/tg/so via quad_perm dpp. (unchanged from R13)
// ---------------------------------------------------------------------------
__global__ __launch_bounds__(256) void fc_lstm_wave(const ushort* __restrict__ featB,
                                                    const float* __restrict__ Wih,
                                                    const float* __restrict__ Whh,
                                                    const float* __restrict__ bih,
                                                    const float* __restrict__ bhh,
                                                    const float* __restrict__ h0,
                                                    const float* __restrict__ c0,
                                                    float* __restrict__ out)
{
  const int tid = threadIdx.x;
  const int l   = tid & 63;
  const int e   = blockIdx.x*4 + (tid >> 6);
  const int u   = l >> 2;                    // unit (valid < 10)
  const int g   = l & 3;                     // gate 0=i 1=f 2=g 3=o
  const int uc  = (u < 10) ? u : 9;
  const bool valid = (u < 10);
  const float sc = (g == 2) ? 2.0f*LOG2E : -LOG2E;
  const int row = g*10 + uc;

  // weights packed f16 pairs: wh2[m] = (W[row][2m], W[row][2m+1]) * sc
  int wh2[5];
#pragma unroll
  for (int m = 0; m < 5; ++m){
    const float w0 = valid ? Whh[row*10 + 2*m]   * sc : 0.0f;
    const float w1 = valid ? Whh[row*10 + 2*m+1] * sc : 0.0f;
    wh2[m] = pkrtz_(w0, w1);
  }
  const float wx   = valid ? Wih[row]*sc : 0.0f;
  const float bia  = valid ? (bih[row] + bhh[row])*sc : 0.0f;
  const float actA = (g == 2) ? 1.0f : 0.0f;
  const float actB = (g == 2) ? -2.0f : 1.0f;

  float c     = valid ? c0[e*10 + uc] : 0.0f;
  float hlast = valid ? h0[e*10 + uc] : 0.0f;

  // h-pair pack: lane 4u gets h[u+1] via DPP row_shl:4 (0x104); pairs read
  // from lanes 0,8,16,24,32 -> (h0,h1),(h2,h3),(h4,h5),(h6,h7),(h8,h9).
  int hp0, hp1, hp2, hp3, hp4;
  {
    const int hn = __builtin_amdgcn_mov_dpp(__float_as_int(hlast), 0x104, 0xF, 0xF, false);
    const int hpi = pkrtz_(hlast, __int_as_float(hn));
    hp0 = __builtin_amdgcn_readlane(hpi,  0);
    hp1 = __builtin_amdgcn_readlane(hpi,  8);
    hp2 = __builtin_amdgcn_readlane(hpi, 16);
    hp3 = __builtin_amdgcn_readlane(hpi, 24);
    hp4 = __builtin_amdgcn_readlane(hpi, 32);
  }

  // ---- scalarized featB pointer (wave-uniform) -> s_load windows -----------
  const uint4* fBs;
  {
    unsigned long long a = (unsigned long long)(uintptr_t)(featB + (size_t)e*512);
    unsigned lo = (unsigned)__builtin_amdgcn_readfirstlane((int)(a & 0xffffffffu));
    unsigned hi = (unsigned)__builtin_amdgcn_readfirstlane((int)(a >> 32));
    fBs = (const uint4*)(uintptr_t)(((unsigned long long)hi << 32) | lo);
  }

  unsigned int cur[8][4], nxt[8][4];   // two 64-step windows (bf16 pairs)
#pragma unroll
  for (int k = 0; k < 8; ++k){
    const uint4 q0 = fBs[k];
    cur[k][0]=q0.x; cur[k][1]=q0.y; cur[k][2]=q0.z; cur[k][3]=q0.w;
    const uint4 q1 = fBs[8 + k];
    nxt[k][0]=q1.x; nxt[k][1]=q1.y; nxt[k][2]=q1.z; nxt[k][3]=q1.w;
  }

  for (int win = 0; win < 8; ++win){
#pragma unroll
    for (int blk = 0; blk < 8; ++blk){
#pragma unroll
      for (int jj = 0; jj < 8; ++jj){
        const unsigned d  = cur[blk][jj >> 1];
        const unsigned xb = (jj & 1) ? (d & 0xffff0000u) : (d << 16);
        const float xs = __int_as_float((int)xb);
        // dot: 1 fma + 5 fdot2 (2 accumulators) + 1 add
        float a0 = __builtin_fmaf(wx, xs, bia);
        a0 = fdot2_(wh2[0], hp0, a0);
        float a1 = fdot2_(wh2[1], hp1, 0.0f);
        a0 = fdot2_(wh2[2], hp2, a0);
        a1 = fdot2_(wh2[3], hp3, a1);
        a0 = fdot2_(wh2[4], hp4, a0);
        const float acc = a0 + a1;
        const float rc  = rcp_(1.0f + ex2_(acc));
        const float val = __builtin_fmaf(actB, rc, actA);
        const int   vi  = __float_as_int(val);
        // gather only sf/tg/so (c,h valid on g==0 lanes only; val there = si)
        const float tg  = __int_as_float(__builtin_amdgcn_mov_dpp(vi, 0xAA, 0xF, 0xF, false));
        const float sf  = __int_as_float(__builtin_amdgcn_mov_dpp(vi, 0x55, 0xF, 0xF, false));
        const float so  = __int_as_float(__builtin_amdgcn_mov_dpp(vi, 0xFF, 0xF, 0xF, false));
        c = __builtin_fmaf(sf, c, val*tg);
        const float tc = __builtin_fmaf(-2.0f, rcp_(1.0f + ex2_(2.0f*LOG2E*c)), 1.0f);
        const float h  = so*tc;
        hlast = h;
        const int hn  = __builtin_amdgcn_mov_dpp(__float_as_int(h), 0x104, 0xF, 0xF, false);
        const int hpi = pkrtz_(h, __int_as_float(hn));
        hp0 = __builtin_amdgcn_readlane(hpi,  0);
        hp1 = __builtin_amdgcn_readlane(hpi,  8);
        hp2 = __builtin_amdgcn_readlane(hpi, 16);
        hp3 = __builtin_amdgcn_readlane(hpi, 24);
        hp4 = __builtin_amdgcn_readlane(hpi, 32);
      }
    }
#pragma unroll
    for (int k = 0; k < 8; ++k){
      cur[k][0]=nxt[k][0]; cur[k][1]=nxt[k][1];
      cur[k][2]=nxt[k][2]; cur[k][3]=nxt[k][3];
    }
    if (win < 6){
#pragma unroll
      for (int k = 0; k < 8; ++k){
        const uint4 q = fBs[(win + 2)*8 + k];
        nxt[k][0]=q.x; nxt[k][1]=q.y; nxt[k][2]=q.z; nxt[k][3]=q.w;
      }
    }
  }

  // ---- log-softmax over units 0..9 (h valid on g==0 lanes) ------------------
  const int hb = __float_as_int(hlast);
  float sh[10];
#pragma unroll
  for (int m = 0; m < 10; ++m)
    sh[m] = __int_as_float(__builtin_amdgcn_readlane(hb, 4*m));
  float mx = sh[0];
#pragma unroll
  for (int m = 1; m < 10; ++m) mx = fmaxf(mx, sh[m]);
  float es = 0.0f;
#pragma unroll
  for (int m = 0; m < 10; ++m) es += ex2_(LOG2E*(sh[m] - mx));
  const float lse = LN2 * lg2_(es);
  if (valid && g == 0) out[e*10 + u] = hlast - mx - lse;
}

extern "C" void kernel_launch(void* const* d_in, const int* in_sizes, int n_in,
                              void* d_out, int out_size, void* d_ws, size_t ws_size,
                              hipStream_t stream)
{
  const float* x = (const float*)d_in[0];
  LstmArgs a;
  const int base[4] = {1, 5, 9, 13};   // lr_f, lr_b, ud_f, ud_b
  for (int d = 0; d < 4; ++d){
    a.Wih[d] = (const float*)d_in[base[d] + 0];
    a.Whh[d] = (const float*)d_in[base[d] + 1];
    a.bih[d] = (const float*)d_in[base[d] + 2];
    a.bhh[d] = (const float*)d_in[base[d] + 3];
  }
  const float* h0lr = (const float*)d_in[21];
  const float* c0lr = (const float*)d_in[22];
  const float* h0ud = (const float*)d_in[23];
  const float* c0ud = (const float*)d_in[24];
  a.h0[0] = h0lr;               a.c0[0] = c0lr;
  a.h0[1] = h0lr + 2048*128;    a.c0[1] = c0lr + 2048*128;
  a.h0[2] = h0ud;               a.c0[2] = c0ud;
  a.h0[3] = h0ud + 2048*128;    a.c0[3] = c0ud + 2048*128;

  char* ws = (char*)d_ws;
  __bf16* featB = (__bf16*)ws;                          // 2048*512*2 = 2 MiB
  bf16x8* wpack = (bf16x8*)(ws + (2u<<20));             // 40960*16 = 640 KiB

  pack_weights<<<160, 256, 0, stream>>>(a, wpack);
  lstm4_kernel<<<512, 512, 0, stream>>>(x, a, wpack, featB);
  fc_lstm_wave<<<512, 256, 0, stream>>>((const ushort*)featB,
      (const float*)d_in[17], (const float*)d_in[18],
      (const float*)d_in[19], (const float*)d_in[20],
      (const float*)d_in[25], (const float*)d_in[26],
      (float*)d_out);
}